// Round 6
// baseline (255.680 us; speedup 1.0000x reference)
//
#include <hip/hip_runtime.h>
#include <hip/hip_bf16.h>

#define N_NODES 50000
#define N_EDGES 1600000
#define N_GRAPHS 512
#define VOCAB 1000
#define EMB 32
#define HID 64
#define N_CLASS 2

#define MAXDEG 96                      // Poisson(32) tail @96 ~ 4e-20/node

// ---- atomic-free CSR build (counting bucket-sort) ----
#define NVEC (N_EDGES / 4)             // 400000 int4 vectors
#define SORT_VPB 1024                  // vectors per block (256 thr x 4)
#define SORT_BLOCKS ((NVEC + SORT_VPB - 1) / SORT_VPB)   // 391
#define BSHIFT 7
#define BUCKET_NODES 128
#define NBUCK ((N_NODES + BUCKET_NODES - 1) / BUCKET_NODES)  // 391
#define CSR_LSTR 100                   // LDS csr row stride (100%32=4 -> bank-spread, 16B-aligned)

#define E1_BLOCKS ((VOCAB * HID + 255) / 256)            // 250

typedef int iv4 __attribute__((ext_vector_type(4)));
typedef unsigned short us;
typedef us usv8 __attribute__((ext_vector_type(8)));
typedef float fv4 __attribute__((ext_vector_type(4)));
typedef unsigned long long u64;

__device__ __forceinline__ float bf2f(us u) {
    union { unsigned int i; float f; } c;
    c.i = ((unsigned int)u) << 16;
    return c.f;
}
__device__ __forceinline__ us f2bf(float f) {
    union { __hip_bfloat16 b; us u; } c;
    c.b = __float2bfloat16(f);
    return c.u;
}
__device__ __forceinline__ float rdlane(float v, int k) {
    return __int_as_float(__builtin_amdgcn_readlane(__float_as_int(v), k));
}

// ---------------- K1: fused precompute_e1 + per-block bucket histogram ----------------
__global__ __launch_bounds__(256) void pre_hist_kernel(
        const int* __restrict__ dst, int* __restrict__ hist,
        const float* __restrict__ embed, const float* __restrict__ w1l,
        const float* __restrict__ w1r, us* __restrict__ e1b,
        float* __restrict__ e1r) {
    __shared__ int lh[NBUCK];
    if (blockIdx.x < SORT_BLOCKS) {
        for (int b = threadIdx.x; b < NBUCK; b += 256) lh[b] = 0;
        __syncthreads();
        const iv4* dst4 = (const iv4*)dst;
        int vbase = blockIdx.x * SORT_VPB;
        #pragma unroll
        for (int t = 0; t < 4; ++t) {
            int v = vbase + t * 256 + threadIdx.x;
            if (v < NVEC) {
                iv4 d4 = __builtin_nontemporal_load(&dst4[v]);
                atomicAdd(&lh[d4.x >> BSHIFT], 1);
                atomicAdd(&lh[d4.y >> BSHIFT], 1);
                atomicAdd(&lh[d4.z >> BSHIFT], 1);
                atomicAdd(&lh[d4.w >> BSHIFT], 1);
            }
        }
        __syncthreads();
        for (int b = threadIdx.x; b < NBUCK; b += 256)
            hist[b * SORT_BLOCKS + blockIdx.x] = lh[b];
    } else {
        int id = (blockIdx.x - SORT_BLOCKS) * 256 + threadIdx.x;
        if (id >= VOCAB * HID) return;
        int v = id >> 6, j = id & 63;
        float a = 0.0f, b = 0.0f;
        #pragma unroll
        for (int k = 0; k < EMB; ++k) {
            float ev = embed[v * EMB + k];
            a = fmaf(ev, w1l[k * HID + j], a);
            b = fmaf(ev, w1r[k * HID + j], b);
        }
        e1b[id] = f2bf(a);
        e1r[id] = b;
    }
}

// ---------------- K2: per-bucket exclusive scan over its SORT_BLOCKS counters ----------------
__global__ __launch_bounds__(256) void scan_rows_kernel(int* __restrict__ hist,
                                                        int* __restrict__ btot) {
    int* row = hist + (size_t)blockIdx.x * SORT_BLOCKS;
    __shared__ int wsum[4];
    int tid = threadIdx.x, lane = tid & 63, w = tid >> 6;
    int carry = 0;
    for (int base = 0; base < SORT_BLOCKS; base += 256) {
        int idx = base + tid;
        int v = (idx < SORT_BLOCKS) ? row[idx] : 0;
        int inc = v;
        #pragma unroll
        for (int off = 1; off < 64; off <<= 1) {
            int n = __shfl_up(inc, off, 64);
            if (lane >= off) inc += n;
        }
        if (lane == 63) wsum[w] = inc;
        __syncthreads();
        int woff = 0;
        #pragma unroll
        for (int k = 0; k < 4; ++k) if (k < w) woff += wsum[k];
        if (idx < SORT_BLOCKS) row[idx] = carry + woff + inc - v;
        carry += wsum[0] + wsum[1] + wsum[2] + wsum[3];
        __syncthreads();
    }
    if (tid == 0) btot[blockIdx.x] = carry;
}

// ---------------- K3: scatter (computes boff locally from btot; block 0 persists it) ----------------
__global__ __launch_bounds__(256) void scatter_kernel(const int* __restrict__ src,
        const int* __restrict__ dst, const int* __restrict__ x_ids,
        const int* __restrict__ hist, const int* __restrict__ btot,
        int* __restrict__ boff, u64* __restrict__ ebuf) {
    __shared__ int lbase[NBUCK];
    __shared__ int wsum[4];
    int tid = threadIdx.x, lane = tid & 63, w = tid >> 6;
    // local exclusive scan of btot[NBUCK] -> lbase
    int carry = 0;
    for (int base = 0; base < NBUCK; base += 256) {
        int idx = base + tid;
        int v = (idx < NBUCK) ? btot[idx] : 0;
        int inc = v;
        #pragma unroll
        for (int off = 1; off < 64; off <<= 1) {
            int n = __shfl_up(inc, off, 64);
            if (lane >= off) inc += n;
        }
        if (lane == 63) wsum[w] = inc;
        __syncthreads();
        int woff = 0;
        #pragma unroll
        for (int k = 0; k < 4; ++k) if (k < w) woff += wsum[k];
        if (idx < NBUCK) lbase[idx] = carry + woff + inc - v;
        carry += wsum[0] + wsum[1] + wsum[2] + wsum[3];
        __syncthreads();
    }
    // block 0 persists boff for K4; all blocks add their per-block hist offset
    for (int b = tid; b < NBUCK; b += 256) {
        if (blockIdx.x == 0) boff[b] = lbase[b];
        lbase[b] += hist[b * SORT_BLOCKS + blockIdx.x];
    }
    if (blockIdx.x == 0 && tid == 0) boff[NBUCK] = carry;
    __syncthreads();
    const iv4* dst4 = (const iv4*)dst;
    const iv4* src4 = (const iv4*)src;
    int vbase = blockIdx.x * SORT_VPB;
    #pragma unroll
    for (int t = 0; t < 4; ++t) {
        int v = vbase + t * 256 + threadIdx.x;
        if (v < NVEC) {
            iv4 d4 = __builtin_nontemporal_load(&dst4[v]);
            iv4 s4 = __builtin_nontemporal_load(&src4[v]);
            int pay0 = (x_ids[s4.x] << 16) | s4.x;
            int pay1 = (x_ids[s4.y] << 16) | s4.y;
            int pay2 = (x_ids[s4.z] << 16) | s4.z;
            int pay3 = (x_ids[s4.w] << 16) | s4.w;
            int p0 = atomicAdd(&lbase[d4.x >> BSHIFT], 1);
            int p1 = atomicAdd(&lbase[d4.y >> BSHIFT], 1);
            int p2 = atomicAdd(&lbase[d4.z >> BSHIFT], 1);
            int p3 = atomicAdd(&lbase[d4.w >> BSHIFT], 1);
            ebuf[p0] = ((u64)(unsigned)d4.x << 32) | (unsigned)pay0;
            ebuf[p1] = ((u64)(unsigned)d4.y << 32) | (unsigned)pay1;
            ebuf[p2] = ((u64)(unsigned)d4.z << 32) | (unsigned)pay2;
            ebuf[p3] = ((u64)(unsigned)d4.w << 32) | (unsigned)pay3;
        }
    }
}

// ---------------- K4: fused CSR build (LDS + global write-through) + layer-1 agg ----------------
__global__ __launch_bounds__(256) void csr_agg1_kernel(const u64* __restrict__ ebuf,
        const int* __restrict__ boff, int* __restrict__ cursor, int* __restrict__ csr,
        const int* __restrict__ x_ids, const us* __restrict__ e1b,
        const float* __restrict__ e1r, const float* __restrict__ b1,
        float* __restrict__ h1, us* __restrict__ h1b, float* __restrict__ gsum) {
    __shared__ int csr_l[BUCKET_NODES * CSR_LSTR];   // 51.2 KB
    __shared__ int cur[BUCKET_NODES];
    int b = blockIdx.x;
    int tid = threadIdx.x;
    for (int r = tid; r < BUCKET_NODES; r += 256) cur[r] = 0;
    // zero gsum (replaces a memset dispatch): blocks 0..127 cover 512*64 floats
    if (b < 128) gsum[b * 256 + tid] = 0.0f;
    __syncthreads();
    int base = boff[b];
    int end  = boff[b + 1];
    int node0 = b << BSHIFT;
    for (int i = base + tid; i < end; i += 256) {
        u64 e = ebuf[i];                               // coalesced read
        int d = (int)(e >> 32);
        int pay = (int)(e & 0xffffffffu);
        int r = d - node0;
        int pos = atomicAdd(&cur[r], 1);               // LDS atomic
        csr_l[r * CSR_LSTR + pos] = pay;               // LDS copy for agg1
        csr[(size_t)d * MAXDEG + pos] = pay;           // global write-through for agg2
    }
    __syncthreads();
    for (int r = tid; r < BUCKET_NODES; r += 256) {
        int d = node0 + r;
        if (d < N_NODES) cursor[d] = cur[r];
    }
    // ---- agg1 phase: 8 lanes/node, csr from LDS ----
    int lane = tid & 63;
    int wv = tid >> 6;
    int g = lane >> 3, c8 = lane & 7;
    for (int slot = wv * 8 + g; slot < BUCKET_NODES; slot += 32) {
        int node = node0 + slot;
        bool valid = node < N_NODES;
        int deg = valid ? cur[slot] : 0;
        const int* crow = csr_l + slot * CSR_LSTR;
        float a0=0.f,a1=0.f,a2=0.f,a3=0.f,a4=0.f,a5=0.f,a6=0.f,a7=0.f;
        for (int k = 0; k < deg; k += 4) {
            iv4 cv = *(const iv4*)(crow + k);          // LDS 16B, broadcast in group
            #define GATH1(CVAL, T)                                                   \
            if (k + (T) < deg) {                                                     \
                int cls = (CVAL) >> 16;                                              \
                usv8 r = *(const usv8*)(e1b + cls * HID + c8 * 8);                   \
                a0 += bf2f(r[0]); a1 += bf2f(r[1]); a2 += bf2f(r[2]); a3 += bf2f(r[3]); \
                a4 += bf2f(r[4]); a5 += bf2f(r[5]); a6 += bf2f(r[6]); a7 += bf2f(r[7]); \
            }
            GATH1(cv.x, 0) GATH1(cv.y, 1) GATH1(cv.z, 2) GATH1(cv.w, 3)
            #undef GATH1
        }
        if (!valid) continue;
        float inv = 1.0f / fmaxf((float)deg, 1.0f);
        int xid = x_ids[node];
        const fv4* er = (const fv4*)(e1r + xid * HID + c8 * 8);
        fv4 e0 = er[0], e1v = er[1];
        const fv4* bb = (const fv4*)(b1 + c8 * 8);
        fv4 b0 = bb[0], b1v = bb[1];
        fv4 h0, h1v;
        h0.x = fmaxf(a0 * inv + b0.x + e0.x, 0.0f);
        h0.y = fmaxf(a1 * inv + b0.y + e0.y, 0.0f);
        h0.z = fmaxf(a2 * inv + b0.z + e0.z, 0.0f);
        h0.w = fmaxf(a3 * inv + b0.w + e0.w, 0.0f);
        h1v.x = fmaxf(a4 * inv + b1v.x + e1v.x, 0.0f);
        h1v.y = fmaxf(a5 * inv + b1v.y + e1v.y, 0.0f);
        h1v.z = fmaxf(a6 * inv + b1v.z + e1v.z, 0.0f);
        h1v.w = fmaxf(a7 * inv + b1v.w + e1v.w, 0.0f);
        int o = node * HID + c8 * 8;
        *(fv4*)(h1 + o) = h0;
        *(fv4*)(h1 + o + 4) = h1v;
        usv8 hb;
        hb[0] = f2bf(h0.x); hb[1] = f2bf(h0.y); hb[2] = f2bf(h0.z); hb[3] = f2bf(h0.w);
        hb[4] = f2bf(h1v.x); hb[5] = f2bf(h1v.y); hb[6] = f2bf(h1v.z); hb[7] = f2bf(h1v.w);
        *(usv8*)(h1b + o) = hb;
    }
}

// ---------------- K5: fused layer-2 agg + linear + relu + pool ----------------
// Phase 1: 8 lanes/node gather mean (registers). LDS transpose. Phase 2: lane=col,
// 128-VGPR weights, rdlane broadcast, pooled atomics. mean2 never materialized.
__global__ __launch_bounds__(256) void agg2_lin2_kernel(
        const us* __restrict__ h1b, const float* __restrict__ h1,
        const int* __restrict__ csr, const int* __restrict__ deg_arr,
        const float* __restrict__ w2l, const float* __restrict__ b2,
        const float* __restrict__ w2r, const int* __restrict__ batch,
        float* __restrict__ gsum) {
    __shared__ float msh[4][8][64];                    // 8 KB: per-wave 8-node mean slab
    int tid = threadIdx.x;
    int lane = tid & 63;
    int wv = tid >> 6;
    int wave_g = (blockIdx.x * 256 + tid) >> 6;
    int n0 = wave_g * 8;
    // weights per lane=column (alive across both phases)
    float wl[HID], wr[HID];
    #pragma unroll
    for (int k = 0; k < HID; ++k) {
        wl[k] = w2l[k * HID + lane];
        wr[k] = w2r[k * HID + lane];
    }
    float bj = b2[lane];
    if (n0 < N_NODES) {
        // ---- phase 1: gather mean for 8 nodes (8 lanes each) ----
        int g = lane >> 3, c8 = lane & 7;
        int node = n0 + g;                             // N_NODES % 8 == 0 -> all valid
        int deg = deg_arr[node];
        const int* crow = csr + (size_t)node * MAXDEG;
        float a0=0.f,a1=0.f,a2=0.f,a3=0.f,a4=0.f,a5=0.f,a6=0.f,a7=0.f;
        for (int k = 0; k < deg; k += 4) {
            iv4 cv = *(const iv4*)(crow + k);
            #define GATH2(CVAL, T)                                                   \
            if (k + (T) < deg) {                                                     \
                int nb = (CVAL) & 0xFFFF;                                            \
                usv8 r = *(const usv8*)(h1b + nb * HID + c8 * 8);                    \
                a0 += bf2f(r[0]); a1 += bf2f(r[1]); a2 += bf2f(r[2]); a3 += bf2f(r[3]); \
                a4 += bf2f(r[4]); a5 += bf2f(r[5]); a6 += bf2f(r[6]); a7 += bf2f(r[7]); \
            }
            GATH2(cv.x, 0) GATH2(cv.y, 1) GATH2(cv.z, 2) GATH2(cv.w, 3)
            #undef GATH2
        }
        float inv = 1.0f / fmaxf((float)deg, 1.0f);
        fv4 m0, m1;
        m0.x = a0 * inv; m0.y = a1 * inv; m0.z = a2 * inv; m0.w = a3 * inv;
        m1.x = a4 * inv; m1.y = a5 * inv; m1.z = a6 * inv; m1.w = a7 * inv;
        *(fv4*)&msh[wv][g][c8 * 8] = m0;
        *(fv4*)&msh[wv][g][c8 * 8 + 4] = m1;
    }
    __syncthreads();
    if (n0 >= N_NODES) return;
    // ---- phase 2: lin2 + relu + pool for the same 8 nodes ----
    int curg = __builtin_amdgcn_readfirstlane(batch[n0]);
    float accp = 0.0f;
    #pragma unroll
    for (int t = 0; t < 8; ++t) {
        int node = n0 + t;
        float m = msh[wv][t][lane];
        float h = h1[node * HID + lane];
        int gg = __builtin_amdgcn_readfirstlane(batch[node]);
        if (gg != curg) {
            atomicAdd(&gsum[curg * HID + lane], accp);
            accp = 0.0f;
            curg = gg;
        }
        float z = bj;
        #pragma unroll
        for (int k = 0; k < HID; ++k)
            z = fmaf(rdlane(m, k), wl[k], fmaf(rdlane(h, k), wr[k], z));
        accp += fmaxf(z, 0.0f);
    }
    atomicAdd(&gsum[curg * HID + lane], accp);
}

// ---------------- K6: output: pool-normalize + final linear ----------------
__global__ void out_kernel(const float* __restrict__ gsum, const int* __restrict__ batch,
                           const float* __restrict__ w_out, const float* __restrict__ b_out,
                           float* __restrict__ out) {
    int id = blockIdx.x * blockDim.x + threadIdx.x;
    if (id >= N_GRAPHS * N_CLASS) return;
    int g = id >> 1, c = id & 1;
    int lo = 0, hi = N_NODES;
    while (lo < hi) { int mid = (lo + hi) >> 1; if (batch[mid] < g) lo = mid + 1; else hi = mid; }
    int first = lo;
    lo = 0; hi = N_NODES;
    while (lo < hi) { int mid = (lo + hi) >> 1; if (batch[mid] <= g) lo = mid + 1; else hi = mid; }
    float cnt = (float)(lo - first);
    float inv = 1.0f / fmaxf(cnt, 1.0f);
    float acc = b_out[c];
    #pragma unroll
    for (int j = 0; j < HID; ++j)
        acc = fmaf(gsum[g * HID + j] * inv, w_out[j * N_CLASS + c], acc);
    out[id] = acc;
}

// ---------------- launch: 6 dispatches ----------------

extern "C" void kernel_launch(void* const* d_in, const int* in_sizes, int n_in,
                              void* d_out, int out_size, void* d_ws, size_t ws_size,
                              hipStream_t stream) {
    const int*   x_ids = (const int*)d_in[0];
    const int*   edge  = (const int*)d_in[1];
    const int*   batch = (const int*)d_in[2];
    const float* embed = (const float*)d_in[3];
    const float* w1l   = (const float*)d_in[4];
    const float* b1    = (const float*)d_in[5];
    const float* w1r   = (const float*)d_in[6];
    const float* w2l   = (const float*)d_in[7];
    const float* b2    = (const float*)d_in[8];
    const float* w2r   = (const float*)d_in[9];
    const float* wout  = (const float*)d_in[10];
    const float* bout  = (const float*)d_in[11];
    const int* src = edge;
    const int* dst = edge + N_EDGES;
    float* out = (float*)d_out;

    char* ws = (char*)d_ws;
    size_t off = 0;
    auto alloc = [&](size_t bytes) -> void* {
        void* p = ws + off;
        off += (bytes + 255) & ~(size_t)255;
        return p;
    };
    float*  h1     = (float*)alloc((size_t)N_NODES * HID * 4);          // 12.8 MB
    us*     h1b    = (us*)alloc((size_t)N_NODES * HID * 2);             // 6.4 MB
    u64*    ebuf   = (u64*)alloc((size_t)N_EDGES * 8);                  // 12.8 MB
    int*    csr    = (int*)alloc((size_t)N_NODES * MAXDEG * 4);         // 19.2 MB
    int*    cursor = (int*)alloc((size_t)N_NODES * 4);                  // 200 KB
    int*    hist   = (int*)alloc((size_t)NBUCK * SORT_BLOCKS * 4);      // 611 KB
    int*    btot   = (int*)alloc((size_t)NBUCK * 4);
    int*    boff   = (int*)alloc((size_t)(NBUCK + 1) * 4);
    us*     e1b    = (us*)alloc((size_t)VOCAB * HID * 2);               // 128 KB
    float*  e1r    = (float*)alloc((size_t)VOCAB * HID * 4);            // 256 KB
    float*  gsum   = (float*)alloc((size_t)N_GRAPHS * HID * 4);         // 128 KB

    const int B = 256;
    pre_hist_kernel<<<SORT_BLOCKS + E1_BLOCKS, B, 0, stream>>>(dst, hist,
                                                               embed, w1l, w1r, e1b, e1r);
    scan_rows_kernel<<<NBUCK, B, 0, stream>>>(hist, btot);
    scatter_kernel<<<SORT_BLOCKS, B, 0, stream>>>(src, dst, x_ids, hist, btot, boff, ebuf);
    csr_agg1_kernel<<<NBUCK, B, 0, stream>>>(ebuf, boff, cursor, csr,
                                             x_ids, e1b, e1r, b1, h1, h1b, gsum);
    agg2_lin2_kernel<<<(N_NODES / 8 + 3) / 4, B, 0, stream>>>(h1b, h1, csr, cursor,
                                                              w2l, b2, w2r, batch, gsum);
    out_kernel<<<(N_GRAPHS * N_CLASS + B - 1) / B, B, 0, stream>>>(gsum, batch, wout, bout, out);
}

// Round 7
// 241.758 us; speedup vs baseline: 1.0576x; 1.0576x over previous
//
#include <hip/hip_runtime.h>
#include <hip/hip_bf16.h>

#define N_NODES 50000
#define N_EDGES 1600000
#define N_GRAPHS 512
#define VOCAB 1000
#define EMB 32
#define HID 64
#define N_CLASS 2

#define MAXDEG 96                      // Poisson(32) tail @96 ~ 4e-20/node

// ---- atomic-free CSR build (counting bucket-sort) ----
#define NVEC (N_EDGES / 4)             // 400000 int4 vectors
#define SORT_VPB 1024                  // vectors per block (256 thr x 4)
#define SORT_BLOCKS ((NVEC + SORT_VPB - 1) / SORT_VPB)   // 391
#define BSHIFT 7
#define BUCKET_NODES 128
#define NBUCK ((N_NODES + BUCKET_NODES - 1) / BUCKET_NODES)  // 391
#define CSR_LSTR 100                   // LDS csr row stride (100%32=4 -> bank-spread, 16B-aligned)

#define E1_BLOCKS ((VOCAB * HID + 255) / 256)            // 250

// ---- agg2: 8 lanes per node, 8 nodes per wave ----
#define AGG_THREADS (N_NODES * 8)
#define AGG_BLOCKS ((AGG_THREADS + 255) / 256)           // 1563

// ---- lin2_pool: weights in VGPRs, 17 nodes per wave ----
#define L2P_BLOCKS 768                 // 3 blocks/CU co-resident
#define L2P_WAVES (L2P_BLOCKS * 4)     // 3072
#define L2P_CHUNK ((N_NODES + L2P_WAVES - 1) / L2P_WAVES)  // 17

typedef int iv4 __attribute__((ext_vector_type(4)));
typedef unsigned short us;
typedef us usv8 __attribute__((ext_vector_type(8)));
typedef float fv4 __attribute__((ext_vector_type(4)));
typedef unsigned long long u64;

__device__ __forceinline__ float bf2f(us u) {
    union { unsigned int i; float f; } c;
    c.i = ((unsigned int)u) << 16;
    return c.f;
}
__device__ __forceinline__ us f2bf(float f) {
    union { __hip_bfloat16 b; us u; } c;
    c.b = __float2bfloat16(f);
    return c.u;
}
__device__ __forceinline__ float rdlane(float v, int k) {
    return __int_as_float(__builtin_amdgcn_readlane(__float_as_int(v), k));
}

// ---------------- K1: fused precompute_e1 + per-block bucket histogram ----------------
__global__ __launch_bounds__(256) void pre_hist_kernel(
        const int* __restrict__ dst, int* __restrict__ hist,
        const float* __restrict__ embed, const float* __restrict__ w1l,
        const float* __restrict__ w1r, us* __restrict__ e1b,
        float* __restrict__ e1r) {
    __shared__ int lh[NBUCK];
    if (blockIdx.x < SORT_BLOCKS) {
        for (int b = threadIdx.x; b < NBUCK; b += 256) lh[b] = 0;
        __syncthreads();
        const iv4* dst4 = (const iv4*)dst;
        int vbase = blockIdx.x * SORT_VPB;
        #pragma unroll
        for (int t = 0; t < 4; ++t) {
            int v = vbase + t * 256 + threadIdx.x;
            if (v < NVEC) {
                iv4 d4 = __builtin_nontemporal_load(&dst4[v]);
                atomicAdd(&lh[d4.x >> BSHIFT], 1);
                atomicAdd(&lh[d4.y >> BSHIFT], 1);
                atomicAdd(&lh[d4.z >> BSHIFT], 1);
                atomicAdd(&lh[d4.w >> BSHIFT], 1);
            }
        }
        __syncthreads();
        for (int b = threadIdx.x; b < NBUCK; b += 256)
            hist[b * SORT_BLOCKS + blockIdx.x] = lh[b];
    } else {
        int id = (blockIdx.x - SORT_BLOCKS) * 256 + threadIdx.x;
        if (id >= VOCAB * HID) return;
        int v = id >> 6, j = id & 63;
        float a = 0.0f, b = 0.0f;
        #pragma unroll
        for (int k = 0; k < EMB; ++k) {
            float ev = embed[v * EMB + k];
            a = fmaf(ev, w1l[k * HID + j], a);
            b = fmaf(ev, w1r[k * HID + j], b);
        }
        e1b[id] = f2bf(a);
        e1r[id] = b;
    }
}

// ---------------- K2: per-bucket exclusive scan over its SORT_BLOCKS counters ----------------
__global__ __launch_bounds__(256) void scan_rows_kernel(int* __restrict__ hist,
                                                        int* __restrict__ btot) {
    int* row = hist + (size_t)blockIdx.x * SORT_BLOCKS;
    __shared__ int wsum[4];
    int tid = threadIdx.x, lane = tid & 63, w = tid >> 6;
    int carry = 0;
    for (int base = 0; base < SORT_BLOCKS; base += 256) {
        int idx = base + tid;
        int v = (idx < SORT_BLOCKS) ? row[idx] : 0;
        int inc = v;
        #pragma unroll
        for (int off = 1; off < 64; off <<= 1) {
            int n = __shfl_up(inc, off, 64);
            if (lane >= off) inc += n;
        }
        if (lane == 63) wsum[w] = inc;
        __syncthreads();
        int woff = 0;
        #pragma unroll
        for (int k = 0; k < 4; ++k) if (k < w) woff += wsum[k];
        if (idx < SORT_BLOCKS) row[idx] = carry + woff + inc - v;
        carry += wsum[0] + wsum[1] + wsum[2] + wsum[3];
        __syncthreads();
    }
    if (tid == 0) btot[blockIdx.x] = carry;
}

// ---------------- K3: scatter (computes boff locally from btot; block 0 persists it) ----------------
__global__ __launch_bounds__(256) void scatter_kernel(const int* __restrict__ src,
        const int* __restrict__ dst, const int* __restrict__ x_ids,
        const int* __restrict__ hist, const int* __restrict__ btot,
        int* __restrict__ boff, u64* __restrict__ ebuf) {
    __shared__ int lbase[NBUCK];
    __shared__ int wsum[4];
    int tid = threadIdx.x, lane = tid & 63, w = tid >> 6;
    // local exclusive scan of btot[NBUCK] -> lbase
    int carry = 0;
    for (int base = 0; base < NBUCK; base += 256) {
        int idx = base + tid;
        int v = (idx < NBUCK) ? btot[idx] : 0;
        int inc = v;
        #pragma unroll
        for (int off = 1; off < 64; off <<= 1) {
            int n = __shfl_up(inc, off, 64);
            if (lane >= off) inc += n;
        }
        if (lane == 63) wsum[w] = inc;
        __syncthreads();
        int woff = 0;
        #pragma unroll
        for (int k = 0; k < 4; ++k) if (k < w) woff += wsum[k];
        if (idx < NBUCK) lbase[idx] = carry + woff + inc - v;
        carry += wsum[0] + wsum[1] + wsum[2] + wsum[3];
        __syncthreads();
    }
    // block 0 persists boff for K4; all blocks add their per-block hist offset
    for (int b = tid; b < NBUCK; b += 256) {
        if (blockIdx.x == 0) boff[b] = lbase[b];
        lbase[b] += hist[b * SORT_BLOCKS + blockIdx.x];
    }
    if (blockIdx.x == 0 && tid == 0) boff[NBUCK] = carry;
    __syncthreads();
    const iv4* dst4 = (const iv4*)dst;
    const iv4* src4 = (const iv4*)src;
    int vbase = blockIdx.x * SORT_VPB;
    #pragma unroll
    for (int t = 0; t < 4; ++t) {
        int v = vbase + t * 256 + threadIdx.x;
        if (v < NVEC) {
            iv4 d4 = __builtin_nontemporal_load(&dst4[v]);
            iv4 s4 = __builtin_nontemporal_load(&src4[v]);
            int pay0 = (x_ids[s4.x] << 16) | s4.x;
            int pay1 = (x_ids[s4.y] << 16) | s4.y;
            int pay2 = (x_ids[s4.z] << 16) | s4.z;
            int pay3 = (x_ids[s4.w] << 16) | s4.w;
            int p0 = atomicAdd(&lbase[d4.x >> BSHIFT], 1);
            int p1 = atomicAdd(&lbase[d4.y >> BSHIFT], 1);
            int p2 = atomicAdd(&lbase[d4.z >> BSHIFT], 1);
            int p3 = atomicAdd(&lbase[d4.w >> BSHIFT], 1);
            ebuf[p0] = ((u64)(unsigned)d4.x << 32) | (unsigned)pay0;
            ebuf[p1] = ((u64)(unsigned)d4.y << 32) | (unsigned)pay1;
            ebuf[p2] = ((u64)(unsigned)d4.z << 32) | (unsigned)pay2;
            ebuf[p3] = ((u64)(unsigned)d4.w << 32) | (unsigned)pay3;
        }
    }
}

// ---------------- K4: fused CSR build (LDS + global write-through) + layer-1 agg ----------------
__global__ __launch_bounds__(256) void csr_agg1_kernel(const u64* __restrict__ ebuf,
        const int* __restrict__ boff, int* __restrict__ cursor, int* __restrict__ csr,
        const int* __restrict__ x_ids, const us* __restrict__ e1b,
        const float* __restrict__ e1r, const float* __restrict__ b1,
        float* __restrict__ h1, us* __restrict__ h1b, float* __restrict__ gsum) {
    __shared__ int csr_l[BUCKET_NODES * CSR_LSTR];   // 51.2 KB
    __shared__ int cur[BUCKET_NODES];
    int b = blockIdx.x;
    int tid = threadIdx.x;
    for (int r = tid; r < BUCKET_NODES; r += 256) cur[r] = 0;
    // zero gsum (replaces a memset dispatch): blocks 0..127 cover 512*64 floats
    if (b < 128) gsum[b * 256 + tid] = 0.0f;
    __syncthreads();
    int base = boff[b];
    int end  = boff[b + 1];
    int node0 = b << BSHIFT;
    for (int i = base + tid; i < end; i += 256) {
        u64 e = ebuf[i];                               // coalesced read
        int d = (int)(e >> 32);
        int pay = (int)(e & 0xffffffffu);
        int r = d - node0;
        int pos = atomicAdd(&cur[r], 1);               // LDS atomic
        csr_l[r * CSR_LSTR + pos] = pay;               // LDS copy for agg1
        csr[(size_t)d * MAXDEG + pos] = pay;           // global write-through for agg2
    }
    __syncthreads();
    for (int r = tid; r < BUCKET_NODES; r += 256) {
        int d = node0 + r;
        if (d < N_NODES) cursor[d] = cur[r];
    }
    // ---- agg1 phase: 8 lanes/node, csr from LDS ----
    int lane = tid & 63;
    int wv = tid >> 6;
    int g = lane >> 3, c8 = lane & 7;
    for (int slot = wv * 8 + g; slot < BUCKET_NODES; slot += 32) {
        int node = node0 + slot;
        bool valid = node < N_NODES;
        int deg = valid ? cur[slot] : 0;
        const int* crow = csr_l + slot * CSR_LSTR;
        float a0=0.f,a1=0.f,a2=0.f,a3=0.f,a4=0.f,a5=0.f,a6=0.f,a7=0.f;
        for (int k = 0; k < deg; k += 4) {
            iv4 cv = *(const iv4*)(crow + k);          // LDS 16B, broadcast in group
            #define GATH1(CVAL, T)                                                   \
            if (k + (T) < deg) {                                                     \
                int cls = (CVAL) >> 16;                                              \
                usv8 r = *(const usv8*)(e1b + cls * HID + c8 * 8);                   \
                a0 += bf2f(r[0]); a1 += bf2f(r[1]); a2 += bf2f(r[2]); a3 += bf2f(r[3]); \
                a4 += bf2f(r[4]); a5 += bf2f(r[5]); a6 += bf2f(r[6]); a7 += bf2f(r[7]); \
            }
            GATH1(cv.x, 0) GATH1(cv.y, 1) GATH1(cv.z, 2) GATH1(cv.w, 3)
            #undef GATH1
        }
        if (!valid) continue;
        float inv = 1.0f / fmaxf((float)deg, 1.0f);
        int xid = x_ids[node];
        const fv4* er = (const fv4*)(e1r + xid * HID + c8 * 8);
        fv4 e0 = er[0], e1v = er[1];
        const fv4* bb = (const fv4*)(b1 + c8 * 8);
        fv4 b0 = bb[0], b1v = bb[1];
        fv4 h0, h1v;
        h0.x = fmaxf(a0 * inv + b0.x + e0.x, 0.0f);
        h0.y = fmaxf(a1 * inv + b0.y + e0.y, 0.0f);
        h0.z = fmaxf(a2 * inv + b0.z + e0.z, 0.0f);
        h0.w = fmaxf(a3 * inv + b0.w + e0.w, 0.0f);
        h1v.x = fmaxf(a4 * inv + b1v.x + e1v.x, 0.0f);
        h1v.y = fmaxf(a5 * inv + b1v.y + e1v.y, 0.0f);
        h1v.z = fmaxf(a6 * inv + b1v.z + e1v.z, 0.0f);
        h1v.w = fmaxf(a7 * inv + b1v.w + e1v.w, 0.0f);
        int o = node * HID + c8 * 8;
        *(fv4*)(h1 + o) = h0;
        *(fv4*)(h1 + o + 4) = h1v;
        usv8 hb;
        hb[0] = f2bf(h0.x); hb[1] = f2bf(h0.y); hb[2] = f2bf(h0.z); hb[3] = f2bf(h0.w);
        hb[4] = f2bf(h1v.x); hb[5] = f2bf(h1v.y); hb[6] = f2bf(h1v.z); hb[7] = f2bf(h1v.w);
        *(usv8*)(h1b + o) = hb;
    }
}

// ---------------- K5: layer-2 aggregation, 8 lanes/node (registers only) ----------------
__global__ __launch_bounds__(256) void agg2_mean_kernel(
        const us* __restrict__ h1b, const int* __restrict__ csr,
        const int* __restrict__ deg_arr, float* __restrict__ mean2) {
    int tid = blockIdx.x * blockDim.x + threadIdx.x;
    int lane = threadIdx.x & 63;
    int g = lane >> 3, c8 = lane & 7;
    int node = (tid >> 6) * 8 + g;
    bool valid = node < N_NODES;
    int nclamp = valid ? node : 0;
    int deg = valid ? deg_arr[nclamp] : 0;
    const int* crow = csr + (size_t)nclamp * MAXDEG;
    float a0=0.f,a1=0.f,a2=0.f,a3=0.f,a4=0.f,a5=0.f,a6=0.f,a7=0.f;
    for (int k = 0; k < deg; k += 4) {
        iv4 cv = *(const iv4*)(crow + k);
        #define GATH2(CVAL, T)                                                   \
        if (k + (T) < deg) {                                                     \
            int nb = (CVAL) & 0xFFFF;                                            \
            usv8 r = *(const usv8*)(h1b + nb * HID + c8 * 8);                    \
            a0 += bf2f(r[0]); a1 += bf2f(r[1]); a2 += bf2f(r[2]); a3 += bf2f(r[3]); \
            a4 += bf2f(r[4]); a5 += bf2f(r[5]); a6 += bf2f(r[6]); a7 += bf2f(r[7]); \
        }
        GATH2(cv.x, 0) GATH2(cv.y, 1) GATH2(cv.z, 2) GATH2(cv.w, 3)
        #undef GATH2
    }
    if (!valid) return;
    float inv = 1.0f / fmaxf((float)deg, 1.0f);
    fv4 m0, m1;
    m0.x = a0 * inv; m0.y = a1 * inv; m0.z = a2 * inv; m0.w = a3 * inv;
    m1.x = a4 * inv; m1.y = a5 * inv; m1.z = a6 * inv; m1.w = a7 * inv;
    int o = node * HID + c8 * 8;
    *(fv4*)(mean2 + o) = m0;
    *(fv4*)(mean2 + o + 4) = m1;
}

// ---------------- K6: layer 2 linear + relu + pool: weights in VGPRs, 17 nodes/wave ----------------
__global__ __launch_bounds__(256) void lin2_pool_kernel(
        const float* __restrict__ mean2, const float* __restrict__ h1,
        const float* __restrict__ w2l, const float* __restrict__ b2,
        const float* __restrict__ w2r, const int* __restrict__ batch,
        float* __restrict__ gsum) {
    int lane = threadIdx.x & 63;
    int wv = (blockIdx.x * blockDim.x + threadIdx.x) >> 6;   // global wave id
    int i0 = wv * L2P_CHUNK;
    int i1 = i0 + L2P_CHUNK; if (i1 > N_NODES) i1 = N_NODES;
    if (i0 >= N_NODES) return;
    float wl[HID], wr[HID];
    #pragma unroll
    for (int k = 0; k < HID; ++k) {
        wl[k] = w2l[k * HID + lane];
        wr[k] = w2r[k * HID + lane];
    }
    float bj = b2[lane];
    int curg = __builtin_amdgcn_readfirstlane(batch[i0]);
    float accp = 0.0f;
    float m = mean2[i0 * HID + lane];
    float h = h1[i0 * HID + lane];
    for (int i = i0; i < i1; ++i) {
        float mn = 0.f, hn = 0.f;
        if (i + 1 < i1) {                      // prefetch next rows
            mn = mean2[(i + 1) * HID + lane];
            hn = h1[(i + 1) * HID + lane];
        }
        int g = __builtin_amdgcn_readfirstlane(batch[i]);
        if (g != curg) {
            atomicAdd(&gsum[curg * HID + lane], accp);
            accp = 0.0f;
            curg = g;
        }
        float z = bj;
        #pragma unroll
        for (int k = 0; k < HID; ++k)
            z = fmaf(rdlane(m, k), wl[k], fmaf(rdlane(h, k), wr[k], z));
        accp += fmaxf(z, 0.0f);
        m = mn; h = hn;
    }
    atomicAdd(&gsum[curg * HID + lane], accp);
}

// ---------------- K7: output: pool-normalize + final linear ----------------
__global__ void out_kernel(const float* __restrict__ gsum, const int* __restrict__ batch,
                           const float* __restrict__ w_out, const float* __restrict__ b_out,
                           float* __restrict__ out) {
    int id = blockIdx.x * blockDim.x + threadIdx.x;
    if (id >= N_GRAPHS * N_CLASS) return;
    int g = id >> 1, c = id & 1;
    int lo = 0, hi = N_NODES;
    while (lo < hi) { int mid = (lo + hi) >> 1; if (batch[mid] < g) lo = mid + 1; else hi = mid; }
    int first = lo;
    lo = 0; hi = N_NODES;
    while (lo < hi) { int mid = (lo + hi) >> 1; if (batch[mid] <= g) lo = mid + 1; else hi = mid; }
    float cnt = (float)(lo - first);
    float inv = 1.0f / fmaxf(cnt, 1.0f);
    float acc = b_out[c];
    #pragma unroll
    for (int j = 0; j < HID; ++j)
        acc = fmaf(gsum[g * HID + j] * inv, w_out[j * N_CLASS + c], acc);
    out[id] = acc;
}

// ---------------- launch: 7 dispatches ----------------

extern "C" void kernel_launch(void* const* d_in, const int* in_sizes, int n_in,
                              void* d_out, int out_size, void* d_ws, size_t ws_size,
                              hipStream_t stream) {
    const int*   x_ids = (const int*)d_in[0];
    const int*   edge  = (const int*)d_in[1];
    const int*   batch = (const int*)d_in[2];
    const float* embed = (const float*)d_in[3];
    const float* w1l   = (const float*)d_in[4];
    const float* b1    = (const float*)d_in[5];
    const float* w1r   = (const float*)d_in[6];
    const float* w2l   = (const float*)d_in[7];
    const float* b2    = (const float*)d_in[8];
    const float* w2r   = (const float*)d_in[9];
    const float* wout  = (const float*)d_in[10];
    const float* bout  = (const float*)d_in[11];
    const int* src = edge;
    const int* dst = edge + N_EDGES;
    float* out = (float*)d_out;

    char* ws = (char*)d_ws;
    size_t off = 0;
    auto alloc = [&](size_t bytes) -> void* {
        void* p = ws + off;
        off += (bytes + 255) & ~(size_t)255;
        return p;
    };
    float*  h1     = (float*)alloc((size_t)N_NODES * HID * 4);          // 12.8 MB
    us*     h1b    = (us*)alloc((size_t)N_NODES * HID * 2);             // 6.4 MB
    u64*    ebuf   = (u64*)alloc((size_t)N_EDGES * 8);                  // 12.8 MB
    int*    csr    = (int*)alloc((size_t)N_NODES * MAXDEG * 4);         // 19.2 MB
    int*    cursor = (int*)alloc((size_t)N_NODES * 4);                  // 200 KB
    int*    hist   = (int*)alloc((size_t)NBUCK * SORT_BLOCKS * 4);      // 611 KB
    int*    btot   = (int*)alloc((size_t)NBUCK * 4);
    int*    boff   = (int*)alloc((size_t)(NBUCK + 1) * 4);
    us*     e1b    = (us*)alloc((size_t)VOCAB * HID * 2);               // 128 KB
    float*  e1r    = (float*)alloc((size_t)VOCAB * HID * 4);            // 256 KB
    float*  gsum   = (float*)alloc((size_t)N_GRAPHS * HID * 4);         // 128 KB

    // mean2 aliases ebuf: ebuf is dead after csr_agg1; agg2_mean then fully
    // overwrites it (exact size match: 1.6M*8B == 50000*64*4B).
    float* mean2 = (float*)ebuf;

    const int B = 256;
    pre_hist_kernel<<<SORT_BLOCKS + E1_BLOCKS, B, 0, stream>>>(dst, hist,
                                                               embed, w1l, w1r, e1b, e1r);
    scan_rows_kernel<<<NBUCK, B, 0, stream>>>(hist, btot);
    scatter_kernel<<<SORT_BLOCKS, B, 0, stream>>>(src, dst, x_ids, hist, btot, boff, ebuf);
    csr_agg1_kernel<<<NBUCK, B, 0, stream>>>(ebuf, boff, cursor, csr,
                                             x_ids, e1b, e1r, b1, h1, h1b, gsum);
    agg2_mean_kernel<<<AGG_BLOCKS, B, 0, stream>>>(h1b, csr, cursor, mean2);
    lin2_pool_kernel<<<L2P_BLOCKS, B, 0, stream>>>(mean2, h1, w2l, b2, w2r, batch, gsum);
    out_kernel<<<(N_GRAPHS * N_CLASS + B - 1) / B, B, 0, stream>>>(gsum, batch, wout, bout, out);
}

// Round 8
// 225.837 us; speedup vs baseline: 1.1321x; 1.0705x over previous
//
#include <hip/hip_runtime.h>
#include <hip/hip_bf16.h>

#define N_NODES 50000
#define N_EDGES 1600000
#define N_GRAPHS 512
#define VOCAB 1000
#define EMB 32
#define HID 64
#define N_CLASS 2

#define MAXDEG 96                      // Poisson(32) tail @96 ~ 4e-20/node

// ---- atomic-free CSR build (counting bucket-sort) ----
#define NVEC (N_EDGES / 4)             // 400000 int4 vectors
#define SORT_VPB 1024                  // vectors per block (256 thr x 4)
#define SORT_BLOCKS ((NVEC + SORT_VPB - 1) / SORT_VPB)   // 391
#define BSHIFT 7
#define BUCKET_NODES 128
#define NBUCK ((N_NODES + BUCKET_NODES - 1) / BUCKET_NODES)  // 391

#define E1_BLOCKS ((VOCAB * HID + 255) / 256)            // 250

// ---- agg kernels: 8 lanes per node, 8 nodes per wave ----
#define AGG_THREADS (N_NODES * 8)
#define AGG_BLOCKS ((AGG_THREADS + 255) / 256)           // 1563

// ---- lin2_pool: weights in VGPRs, 17 nodes per wave ----
#define L2P_BLOCKS 768                 // 3 blocks/CU co-resident
#define L2P_WAVES (L2P_BLOCKS * 4)     // 3072
#define L2P_CHUNK ((N_NODES + L2P_WAVES - 1) / L2P_WAVES)  // 17

typedef int iv4 __attribute__((ext_vector_type(4)));
typedef unsigned short us;
typedef us usv8 __attribute__((ext_vector_type(8)));
typedef float fv4 __attribute__((ext_vector_type(4)));
typedef unsigned long long u64;

__device__ __forceinline__ float bf2f(us u) {
    union { unsigned int i; float f; } c;
    c.i = ((unsigned int)u) << 16;
    return c.f;
}
__device__ __forceinline__ us f2bf(float f) {
    union { __hip_bfloat16 b; us u; } c;
    c.b = __float2bfloat16(f);
    return c.u;
}
__device__ __forceinline__ float rdlane(float v, int k) {
    return __int_as_float(__builtin_amdgcn_readlane(__float_as_int(v), k));
}

// ---------------- K1: fused precompute_e1 + per-block bucket histogram ----------------
__global__ __launch_bounds__(256) void pre_hist_kernel(
        const int* __restrict__ dst, int* __restrict__ hist,
        const float* __restrict__ embed, const float* __restrict__ w1l,
        const float* __restrict__ w1r, us* __restrict__ e1b,
        float* __restrict__ e1r) {
    __shared__ int lh[NBUCK];
    if (blockIdx.x < SORT_BLOCKS) {
        for (int b = threadIdx.x; b < NBUCK; b += 256) lh[b] = 0;
        __syncthreads();
        const iv4* dst4 = (const iv4*)dst;
        int vbase = blockIdx.x * SORT_VPB;
        #pragma unroll
        for (int t = 0; t < 4; ++t) {
            int v = vbase + t * 256 + threadIdx.x;
            if (v < NVEC) {
                iv4 d4 = __builtin_nontemporal_load(&dst4[v]);
                atomicAdd(&lh[d4.x >> BSHIFT], 1);
                atomicAdd(&lh[d4.y >> BSHIFT], 1);
                atomicAdd(&lh[d4.z >> BSHIFT], 1);
                atomicAdd(&lh[d4.w >> BSHIFT], 1);
            }
        }
        __syncthreads();
        for (int b = threadIdx.x; b < NBUCK; b += 256)
            hist[b * SORT_BLOCKS + blockIdx.x] = lh[b];
    } else {
        int id = (blockIdx.x - SORT_BLOCKS) * 256 + threadIdx.x;
        if (id >= VOCAB * HID) return;
        int v = id >> 6, j = id & 63;
        float a = 0.0f, b = 0.0f;
        #pragma unroll
        for (int k = 0; k < EMB; ++k) {
            float ev = embed[v * EMB + k];
            a = fmaf(ev, w1l[k * HID + j], a);
            b = fmaf(ev, w1r[k * HID + j], b);
        }
        e1b[id] = f2bf(a);
        e1r[id] = b;
    }
}

// ---------------- K2: per-bucket exclusive scan over its SORT_BLOCKS counters ----------------
__global__ __launch_bounds__(256) void scan_rows_kernel(int* __restrict__ hist,
                                                        int* __restrict__ btot) {
    int* row = hist + (size_t)blockIdx.x * SORT_BLOCKS;
    __shared__ int wsum[4];
    int tid = threadIdx.x, lane = tid & 63, w = tid >> 6;
    int carry = 0;
    for (int base = 0; base < SORT_BLOCKS; base += 256) {
        int idx = base + tid;
        int v = (idx < SORT_BLOCKS) ? row[idx] : 0;
        int inc = v;
        #pragma unroll
        for (int off = 1; off < 64; off <<= 1) {
            int n = __shfl_up(inc, off, 64);
            if (lane >= off) inc += n;
        }
        if (lane == 63) wsum[w] = inc;
        __syncthreads();
        int woff = 0;
        #pragma unroll
        for (int k = 0; k < 4; ++k) if (k < w) woff += wsum[k];
        if (idx < SORT_BLOCKS) row[idx] = carry + woff + inc - v;
        carry += wsum[0] + wsum[1] + wsum[2] + wsum[3];
        __syncthreads();
    }
    if (tid == 0) btot[blockIdx.x] = carry;
}

// ---------------- K3: scatter (computes boff locally from btot; block 0 persists it) ----------------
__global__ __launch_bounds__(256) void scatter_kernel(const int* __restrict__ src,
        const int* __restrict__ dst, const int* __restrict__ x_ids,
        const int* __restrict__ hist, const int* __restrict__ btot,
        int* __restrict__ boff, u64* __restrict__ ebuf) {
    __shared__ int lbase[NBUCK];
    __shared__ int wsum[4];
    int tid = threadIdx.x, lane = tid & 63, w = tid >> 6;
    // local exclusive scan of btot[NBUCK] -> lbase
    int carry = 0;
    for (int base = 0; base < NBUCK; base += 256) {
        int idx = base + tid;
        int v = (idx < NBUCK) ? btot[idx] : 0;
        int inc = v;
        #pragma unroll
        for (int off = 1; off < 64; off <<= 1) {
            int n = __shfl_up(inc, off, 64);
            if (lane >= off) inc += n;
        }
        if (lane == 63) wsum[w] = inc;
        __syncthreads();
        int woff = 0;
        #pragma unroll
        for (int k = 0; k < 4; ++k) if (k < w) woff += wsum[k];
        if (idx < NBUCK) lbase[idx] = carry + woff + inc - v;
        carry += wsum[0] + wsum[1] + wsum[2] + wsum[3];
        __syncthreads();
    }
    // block 0 persists boff for K4/K5; all blocks add their per-block hist offset
    for (int b = tid; b < NBUCK; b += 256) {
        if (blockIdx.x == 0) boff[b] = lbase[b];
        lbase[b] += hist[b * SORT_BLOCKS + blockIdx.x];
    }
    if (blockIdx.x == 0 && tid == 0) boff[NBUCK] = carry;
    __syncthreads();
    const iv4* dst4 = (const iv4*)dst;
    const iv4* src4 = (const iv4*)src;
    int vbase = blockIdx.x * SORT_VPB;
    #pragma unroll
    for (int t = 0; t < 4; ++t) {
        int v = vbase + t * 256 + threadIdx.x;
        if (v < NVEC) {
            iv4 d4 = __builtin_nontemporal_load(&dst4[v]);
            iv4 s4 = __builtin_nontemporal_load(&src4[v]);
            int pay0 = (x_ids[s4.x] << 16) | s4.x;
            int pay1 = (x_ids[s4.y] << 16) | s4.y;
            int pay2 = (x_ids[s4.z] << 16) | s4.z;
            int pay3 = (x_ids[s4.w] << 16) | s4.w;
            int p0 = atomicAdd(&lbase[d4.x >> BSHIFT], 1);
            int p1 = atomicAdd(&lbase[d4.y >> BSHIFT], 1);
            int p2 = atomicAdd(&lbase[d4.z >> BSHIFT], 1);
            int p3 = atomicAdd(&lbase[d4.w >> BSHIFT], 1);
            ebuf[p0] = ((u64)(unsigned)d4.x << 32) | (unsigned)pay0;
            ebuf[p1] = ((u64)(unsigned)d4.y << 32) | (unsigned)pay1;
            ebuf[p2] = ((u64)(unsigned)d4.z << 32) | (unsigned)pay2;
            ebuf[p3] = ((u64)(unsigned)d4.w << 32) | (unsigned)pay3;
        }
    }
}

// ---------------- K4: per-bucket CSR build (LDS cursors only, 512B LDS) ----------------
__global__ __launch_bounds__(256) void csr_bucket_kernel(const u64* __restrict__ ebuf,
        const int* __restrict__ boff, int* __restrict__ cursor, int* __restrict__ csr,
        float* __restrict__ gsum) {
    int b = blockIdx.x;
    int tid = threadIdx.x;
    __shared__ int cur[BUCKET_NODES];
    for (int r = tid; r < BUCKET_NODES; r += 256) cur[r] = 0;
    // zero gsum (replaces a memset dispatch): blocks 0..127 cover 512*64 floats
    if (b < 128) gsum[b * 256 + tid] = 0.0f;
    __syncthreads();
    int base = boff[b];
    int end  = boff[b + 1];
    int node0 = b << BSHIFT;
    for (int i = base + tid; i < end; i += 256) {
        u64 e = ebuf[i];                               // coalesced 8B read
        int d = (int)(e >> 32);
        int pay = (int)(e & 0xffffffffu);
        int pos = atomicAdd(&cur[d - node0], 1);       // LDS atomic
        csr[(size_t)d * MAXDEG + pos] = pay;           // store within 49KB L2-local slab
    }
    __syncthreads();
    for (int r = tid; r < BUCKET_NODES; r += 256) {
        int d = node0 + r;
        if (d < N_NODES) cursor[d] = cur[r];
    }
}

// ---------------- K5: layer 1 agg + linear + relu, 8 lanes/node ----------------
__global__ __launch_bounds__(256) void agg1_lin1_kernel(
        const int* __restrict__ x_ids, const int* __restrict__ csr,
        const int* __restrict__ deg_arr, const us* __restrict__ e1b,
        const float* __restrict__ e1r, const float* __restrict__ b1,
        float* __restrict__ h1, us* __restrict__ h1b) {
    int tid = blockIdx.x * blockDim.x + threadIdx.x;
    int lane = threadIdx.x & 63;
    int g = lane >> 3, c8 = lane & 7;
    int node = (tid >> 6) * 8 + g;
    bool valid = node < N_NODES;
    int nclamp = valid ? node : 0;
    int deg = valid ? deg_arr[nclamp] : 0;
    const int* crow = csr + (size_t)nclamp * MAXDEG;
    float a0=0.f,a1=0.f,a2=0.f,a3=0.f,a4=0.f,a5=0.f,a6=0.f,a7=0.f;
    for (int k = 0; k < deg; k += 4) {
        iv4 cv = *(const iv4*)(crow + k);      // 16B idx batch, broadcast within group
        #define GATH1(CVAL, T)                                                   \
        if (k + (T) < deg) {                                                     \
            int cls = (CVAL) >> 16;                                              \
            usv8 r = *(const usv8*)(e1b + cls * HID + c8 * 8);                   \
            a0 += bf2f(r[0]); a1 += bf2f(r[1]); a2 += bf2f(r[2]); a3 += bf2f(r[3]); \
            a4 += bf2f(r[4]); a5 += bf2f(r[5]); a6 += bf2f(r[6]); a7 += bf2f(r[7]); \
        }
        GATH1(cv.x, 0) GATH1(cv.y, 1) GATH1(cv.z, 2) GATH1(cv.w, 3)
        #undef GATH1
    }
    if (!valid) return;
    float inv = 1.0f / fmaxf((float)deg, 1.0f);
    int xid = x_ids[nclamp];
    const fv4* er = (const fv4*)(e1r + xid * HID + c8 * 8);
    fv4 e0 = er[0], e1v = er[1];
    const fv4* bb = (const fv4*)(b1 + c8 * 8);
    fv4 b0 = bb[0], b1v = bb[1];
    fv4 h0, h1v;
    h0.x = fmaxf(a0 * inv + b0.x + e0.x, 0.0f);
    h0.y = fmaxf(a1 * inv + b0.y + e0.y, 0.0f);
    h0.z = fmaxf(a2 * inv + b0.z + e0.z, 0.0f);
    h0.w = fmaxf(a3 * inv + b0.w + e0.w, 0.0f);
    h1v.x = fmaxf(a4 * inv + b1v.x + e1v.x, 0.0f);
    h1v.y = fmaxf(a5 * inv + b1v.y + e1v.y, 0.0f);
    h1v.z = fmaxf(a6 * inv + b1v.z + e1v.z, 0.0f);
    h1v.w = fmaxf(a7 * inv + b1v.w + e1v.w, 0.0f);
    int o = node * HID + c8 * 8;
    *(fv4*)(h1 + o) = h0;
    *(fv4*)(h1 + o + 4) = h1v;
    usv8 hb;
    hb[0] = f2bf(h0.x); hb[1] = f2bf(h0.y); hb[2] = f2bf(h0.z); hb[3] = f2bf(h0.w);
    hb[4] = f2bf(h1v.x); hb[5] = f2bf(h1v.y); hb[6] = f2bf(h1v.z); hb[7] = f2bf(h1v.w);
    *(usv8*)(h1b + o) = hb;
}

// ---------------- K6: layer-2 aggregation, 8 lanes/node (registers only) ----------------
__global__ __launch_bounds__(256) void agg2_mean_kernel(
        const us* __restrict__ h1b, const int* __restrict__ csr,
        const int* __restrict__ deg_arr, float* __restrict__ mean2) {
    int tid = blockIdx.x * blockDim.x + threadIdx.x;
    int lane = threadIdx.x & 63;
    int g = lane >> 3, c8 = lane & 7;
    int node = (tid >> 6) * 8 + g;
    bool valid = node < N_NODES;
    int nclamp = valid ? node : 0;
    int deg = valid ? deg_arr[nclamp] : 0;
    const int* crow = csr + (size_t)nclamp * MAXDEG;
    float a0=0.f,a1=0.f,a2=0.f,a3=0.f,a4=0.f,a5=0.f,a6=0.f,a7=0.f;
    for (int k = 0; k < deg; k += 4) {
        iv4 cv = *(const iv4*)(crow + k);
        #define GATH2(CVAL, T)                                                   \
        if (k + (T) < deg) {                                                     \
            int nb = (CVAL) & 0xFFFF;                                            \
            usv8 r = *(const usv8*)(h1b + nb * HID + c8 * 8);                    \
            a0 += bf2f(r[0]); a1 += bf2f(r[1]); a2 += bf2f(r[2]); a3 += bf2f(r[3]); \
            a4 += bf2f(r[4]); a5 += bf2f(r[5]); a6 += bf2f(r[6]); a7 += bf2f(r[7]); \
        }
        GATH2(cv.x, 0) GATH2(cv.y, 1) GATH2(cv.z, 2) GATH2(cv.w, 3)
        #undef GATH2
    }
    if (!valid) return;
    float inv = 1.0f / fmaxf((float)deg, 1.0f);
    fv4 m0, m1;
    m0.x = a0 * inv; m0.y = a1 * inv; m0.z = a2 * inv; m0.w = a3 * inv;
    m1.x = a4 * inv; m1.y = a5 * inv; m1.z = a6 * inv; m1.w = a7 * inv;
    int o = node * HID + c8 * 8;
    *(fv4*)(mean2 + o) = m0;
    *(fv4*)(mean2 + o + 4) = m1;
}

// ---------------- K7: layer 2 linear + relu + pool: weights in VGPRs, 17 nodes/wave ----------------
__global__ __launch_bounds__(256) void lin2_pool_kernel(
        const float* __restrict__ mean2, const float* __restrict__ h1,
        const float* __restrict__ w2l, const float* __restrict__ b2,
        const float* __restrict__ w2r, const int* __restrict__ batch,
        float* __restrict__ gsum) {
    int lane = threadIdx.x & 63;
    int wv = (blockIdx.x * blockDim.x + threadIdx.x) >> 6;   // global wave id
    int i0 = wv * L2P_CHUNK;
    int i1 = i0 + L2P_CHUNK; if (i1 > N_NODES) i1 = N_NODES;
    if (i0 >= N_NODES) return;
    float wl[HID], wr[HID];
    #pragma unroll
    for (int k = 0; k < HID; ++k) {
        wl[k] = w2l[k * HID + lane];
        wr[k] = w2r[k * HID + lane];
    }
    float bj = b2[lane];
    int curg = __builtin_amdgcn_readfirstlane(batch[i0]);
    float accp = 0.0f;
    float m = mean2[i0 * HID + lane];
    float h = h1[i0 * HID + lane];
    for (int i = i0; i < i1; ++i) {
        float mn = 0.f, hn = 0.f;
        if (i + 1 < i1) {                      // prefetch next rows
            mn = mean2[(i + 1) * HID + lane];
            hn = h1[(i + 1) * HID + lane];
        }
        int g = __builtin_amdgcn_readfirstlane(batch[i]);
        if (g != curg) {
            atomicAdd(&gsum[curg * HID + lane], accp);
            accp = 0.0f;
            curg = g;
        }
        float z = bj;
        #pragma unroll
        for (int k = 0; k < HID; ++k)
            z = fmaf(rdlane(m, k), wl[k], fmaf(rdlane(h, k), wr[k], z));
        accp += fmaxf(z, 0.0f);
        m = mn; h = hn;
    }
    atomicAdd(&gsum[curg * HID + lane], accp);
}

// ---------------- K8: output: pool-normalize + final linear ----------------
__global__ void out_kernel(const float* __restrict__ gsum, const int* __restrict__ batch,
                           const float* __restrict__ w_out, const float* __restrict__ b_out,
                           float* __restrict__ out) {
    int id = blockIdx.x * blockDim.x + threadIdx.x;
    if (id >= N_GRAPHS * N_CLASS) return;
    int g = id >> 1, c = id & 1;
    int lo = 0, hi = N_NODES;
    while (lo < hi) { int mid = (lo + hi) >> 1; if (batch[mid] < g) lo = mid + 1; else hi = mid; }
    int first = lo;
    lo = 0; hi = N_NODES;
    while (lo < hi) { int mid = (lo + hi) >> 1; if (batch[mid] <= g) lo = mid + 1; else hi = mid; }
    float cnt = (float)(lo - first);
    float inv = 1.0f / fmaxf(cnt, 1.0f);
    float acc = b_out[c];
    #pragma unroll
    for (int j = 0; j < HID; ++j)
        acc = fmaf(gsum[g * HID + j] * inv, w_out[j * N_CLASS + c], acc);
    out[id] = acc;
}

// ---------------- launch: 8 dispatches ----------------

extern "C" void kernel_launch(void* const* d_in, const int* in_sizes, int n_in,
                              void* d_out, int out_size, void* d_ws, size_t ws_size,
                              hipStream_t stream) {
    const int*   x_ids = (const int*)d_in[0];
    const int*   edge  = (const int*)d_in[1];
    const int*   batch = (const int*)d_in[2];
    const float* embed = (const float*)d_in[3];
    const float* w1l   = (const float*)d_in[4];
    const float* b1    = (const float*)d_in[5];
    const float* w1r   = (const float*)d_in[6];
    const float* w2l   = (const float*)d_in[7];
    const float* b2    = (const float*)d_in[8];
    const float* w2r   = (const float*)d_in[9];
    const float* wout  = (const float*)d_in[10];
    const float* bout  = (const float*)d_in[11];
    const int* src = edge;
    const int* dst = edge + N_EDGES;
    float* out = (float*)d_out;

    char* ws = (char*)d_ws;
    size_t off = 0;
    auto alloc = [&](size_t bytes) -> void* {
        void* p = ws + off;
        off += (bytes + 255) & ~(size_t)255;
        return p;
    };
    float*  h1     = (float*)alloc((size_t)N_NODES * HID * 4);          // 12.8 MB
    us*     h1b    = (us*)alloc((size_t)N_NODES * HID * 2);             // 6.4 MB
    u64*    ebuf   = (u64*)alloc((size_t)N_EDGES * 8);                  // 12.8 MB
    int*    csr    = (int*)alloc((size_t)N_NODES * MAXDEG * 4);         // 19.2 MB
    int*    cursor = (int*)alloc((size_t)N_NODES * 4);                  // 200 KB
    int*    hist   = (int*)alloc((size_t)NBUCK * SORT_BLOCKS * 4);      // 611 KB
    int*    btot   = (int*)alloc((size_t)NBUCK * 4);
    int*    boff   = (int*)alloc((size_t)(NBUCK + 1) * 4);
    us*     e1b    = (us*)alloc((size_t)VOCAB * HID * 2);               // 128 KB
    float*  e1r    = (float*)alloc((size_t)VOCAB * HID * 4);            // 256 KB
    float*  gsum   = (float*)alloc((size_t)N_GRAPHS * HID * 4);         // 128 KB

    // mean2 aliases ebuf: ebuf is dead after csr_bucket; agg2_mean then fully
    // overwrites it (exact size match: 1.6M*8B == 50000*64*4B).
    float* mean2 = (float*)ebuf;

    const int B = 256;
    pre_hist_kernel<<<SORT_BLOCKS + E1_BLOCKS, B, 0, stream>>>(dst, hist,
                                                               embed, w1l, w1r, e1b, e1r);
    scan_rows_kernel<<<NBUCK, B, 0, stream>>>(hist, btot);
    scatter_kernel<<<SORT_BLOCKS, B, 0, stream>>>(src, dst, x_ids, hist, btot, boff, ebuf);
    csr_bucket_kernel<<<NBUCK, B, 0, stream>>>(ebuf, boff, cursor, csr, gsum);
    agg1_lin1_kernel<<<AGG_BLOCKS, B, 0, stream>>>(x_ids, csr, cursor,
                                                   e1b, e1r, b1, h1, h1b);
    agg2_mean_kernel<<<AGG_BLOCKS, B, 0, stream>>>(h1b, csr, cursor, mean2);
    lin2_pool_kernel<<<L2P_BLOCKS, B, 0, stream>>>(mean2, h1, w2l, b2, w2r, batch, gsum);
    out_kernel<<<(N_GRAPHS * N_CLASS + B - 1) / B, B, 0, stream>>>(gsum, batch, wout, bout, out);
}

// Round 11
// 218.922 us; speedup vs baseline: 1.1679x; 1.0316x over previous
//
#include <hip/hip_runtime.h>
#include <hip/hip_bf16.h>

#define N_NODES 50000
#define N_EDGES 1600000
#define N_GRAPHS 512
#define VOCAB 1000
#define EMB 32
#define HID 64
#define N_CLASS 2

#define MAXDEG 96                      // Poisson(32) tail @96 ~ 4e-20/node

// ---- atomic-free CSR build (counting bucket-sort) ----
#define NVEC (N_EDGES / 4)             // 400000 int4 vectors
#define SORT_VPB 1024                  // vectors per block (256 thr x 4)
#define SORT_BLOCKS ((NVEC + SORT_VPB - 1) / SORT_VPB)   // 391
#define BSHIFT 7
#define BUCKET_NODES 128
#define NBUCK ((N_NODES + BUCKET_NODES - 1) / BUCKET_NODES)  // 391

#define E1_BLOCKS ((VOCAB * HID + 255) / 256)            // 250

// ---- agg kernels: 8 lanes per node, 8 nodes per wave ----
#define AGG_THREADS (N_NODES * 8)
#define AGG_BLOCKS ((AGG_THREADS + 255) / 256)           // 1563

// ---- lin2_pool: weights in VGPRs, 17 nodes per wave ----
#define L2P_BLOCKS 768                 // 3 blocks/CU co-resident
#define L2P_WAVES (L2P_BLOCKS * 4)     // 3072
#define L2P_CHUNK ((N_NODES + L2P_WAVES - 1) / L2P_WAVES)  // 17

typedef int iv4 __attribute__((ext_vector_type(4)));
typedef unsigned short us;
typedef us usv8 __attribute__((ext_vector_type(8)));
typedef float fv4 __attribute__((ext_vector_type(4)));
typedef unsigned long long u64;

__device__ __forceinline__ float bf2f(us u) {
    union { unsigned int i; float f; } c;
    c.i = ((unsigned int)u) << 16;
    return c.f;
}
__device__ __forceinline__ us f2bf(float f) {
    union { __hip_bfloat16 b; us u; } c;
    c.b = __float2bfloat16(f);
    return c.u;
}
__device__ __forceinline__ float rdlane(float v, int k) {
    return __int_as_float(__builtin_amdgcn_readlane(__float_as_int(v), k));
}

// ---------------- K1: fused precompute_e1 + per-block bucket histogram ----------------
__global__ __launch_bounds__(256) void pre_hist_kernel(
        const int* __restrict__ dst, int* __restrict__ hist,
        const float* __restrict__ embed, const float* __restrict__ w1l,
        const float* __restrict__ w1r, us* __restrict__ e1b,
        float* __restrict__ e1r) {
    __shared__ int lh[NBUCK];
    if (blockIdx.x < SORT_BLOCKS) {
        for (int b = threadIdx.x; b < NBUCK; b += 256) lh[b] = 0;
        __syncthreads();
        const iv4* dst4 = (const iv4*)dst;
        int vbase = blockIdx.x * SORT_VPB;
        #pragma unroll
        for (int t = 0; t < 4; ++t) {
            int v = vbase + t * 256 + threadIdx.x;
            if (v < NVEC) {
                iv4 d4 = __builtin_nontemporal_load(&dst4[v]);
                atomicAdd(&lh[d4.x >> BSHIFT], 1);
                atomicAdd(&lh[d4.y >> BSHIFT], 1);
                atomicAdd(&lh[d4.z >> BSHIFT], 1);
                atomicAdd(&lh[d4.w >> BSHIFT], 1);
            }
        }
        __syncthreads();
        for (int b = threadIdx.x; b < NBUCK; b += 256)
            hist[b * SORT_BLOCKS + blockIdx.x] = lh[b];
    } else {
        int id = (blockIdx.x - SORT_BLOCKS) * 256 + threadIdx.x;
        if (id >= VOCAB * HID) return;
        int v = id >> 6, j = id & 63;
        float a = 0.0f, b = 0.0f;
        #pragma unroll
        for (int k = 0; k < EMB; ++k) {
            float ev = embed[v * EMB + k];
            a = fmaf(ev, w1l[k * HID + j], a);
            b = fmaf(ev, w1r[k * HID + j], b);
        }
        e1b[id] = f2bf(a);
        e1r[id] = b;
    }
}

// ---------------- K2: per-bucket exclusive scan over its SORT_BLOCKS counters ----------------
__global__ __launch_bounds__(256) void scan_rows_kernel(int* __restrict__ hist,
                                                        int* __restrict__ btot) {
    int* row = hist + (size_t)blockIdx.x * SORT_BLOCKS;
    __shared__ int wsum[4];
    int tid = threadIdx.x, lane = tid & 63, w = tid >> 6;
    int carry = 0;
    for (int base = 0; base < SORT_BLOCKS; base += 256) {
        int idx = base + tid;
        int v = (idx < SORT_BLOCKS) ? row[idx] : 0;
        int inc = v;
        #pragma unroll
        for (int off = 1; off < 64; off <<= 1) {
            int n = __shfl_up(inc, off, 64);
            if (lane >= off) inc += n;
        }
        if (lane == 63) wsum[w] = inc;
        __syncthreads();
        int woff = 0;
        #pragma unroll
        for (int k = 0; k < 4; ++k) if (k < w) woff += wsum[k];
        if (idx < SORT_BLOCKS) row[idx] = carry + woff + inc - v;
        carry += wsum[0] + wsum[1] + wsum[2] + wsum[3];
        __syncthreads();
    }
    if (tid == 0) btot[blockIdx.x] = carry;
}

// ---------------- K3: scatter (computes boff locally from btot; block 0 persists it) ----------------
__global__ __launch_bounds__(256) void scatter_kernel(const int* __restrict__ src,
        const int* __restrict__ dst, const int* __restrict__ x_ids,
        const int* __restrict__ hist, const int* __restrict__ btot,
        int* __restrict__ boff, u64* __restrict__ ebuf) {
    __shared__ int lbase[NBUCK];
    __shared__ int wsum[4];
    int tid = threadIdx.x, lane = tid & 63, w = tid >> 6;
    // local exclusive scan of btot[NBUCK] -> lbase
    int carry = 0;
    for (int base = 0; base < NBUCK; base += 256) {
        int idx = base + tid;
        int v = (idx < NBUCK) ? btot[idx] : 0;
        int inc = v;
        #pragma unroll
        for (int off = 1; off < 64; off <<= 1) {
            int n = __shfl_up(inc, off, 64);
            if (lane >= off) inc += n;
        }
        if (lane == 63) wsum[w] = inc;
        __syncthreads();
        int woff = 0;
        #pragma unroll
        for (int k = 0; k < 4; ++k) if (k < w) woff += wsum[k];
        if (idx < NBUCK) lbase[idx] = carry + woff + inc - v;
        carry += wsum[0] + wsum[1] + wsum[2] + wsum[3];
        __syncthreads();
    }
    // block 0 persists boff for K4; all blocks add their per-block hist offset
    for (int b = tid; b < NBUCK; b += 256) {
        if (blockIdx.x == 0) boff[b] = lbase[b];
        lbase[b] += hist[b * SORT_BLOCKS + blockIdx.x];
    }
    if (blockIdx.x == 0 && tid == 0) boff[NBUCK] = carry;
    __syncthreads();
    const iv4* dst4 = (const iv4*)dst;
    const iv4* src4 = (const iv4*)src;
    int vbase = blockIdx.x * SORT_VPB;
    #pragma unroll
    for (int t = 0; t < 4; ++t) {
        int v = vbase + t * 256 + threadIdx.x;
        if (v < NVEC) {
            iv4 d4 = __builtin_nontemporal_load(&dst4[v]);
            iv4 s4 = __builtin_nontemporal_load(&src4[v]);
            int pay0 = (x_ids[s4.x] << 16) | s4.x;
            int pay1 = (x_ids[s4.y] << 16) | s4.y;
            int pay2 = (x_ids[s4.z] << 16) | s4.z;
            int pay3 = (x_ids[s4.w] << 16) | s4.w;
            int p0 = atomicAdd(&lbase[d4.x >> BSHIFT], 1);
            int p1 = atomicAdd(&lbase[d4.y >> BSHIFT], 1);
            int p2 = atomicAdd(&lbase[d4.z >> BSHIFT], 1);
            int p3 = atomicAdd(&lbase[d4.w >> BSHIFT], 1);
            ebuf[p0] = ((u64)(unsigned)d4.x << 32) | (unsigned)pay0;
            ebuf[p1] = ((u64)(unsigned)d4.y << 32) | (unsigned)pay1;
            ebuf[p2] = ((u64)(unsigned)d4.z << 32) | (unsigned)pay2;
            ebuf[p3] = ((u64)(unsigned)d4.w << 32) | (unsigned)pay3;
        }
    }
}

// ---------------- K4: per-bucket CSR build (LDS cursors only, 512B LDS) ----------------
__global__ __launch_bounds__(256) void csr_bucket_kernel(const u64* __restrict__ ebuf,
        const int* __restrict__ boff, int* __restrict__ cursor, int* __restrict__ csr,
        float* __restrict__ gsum) {
    int b = blockIdx.x;
    int tid = threadIdx.x;
    __shared__ int cur[BUCKET_NODES];
    for (int r = tid; r < BUCKET_NODES; r += 256) cur[r] = 0;
    // zero gsum (replaces a memset dispatch): blocks 0..127 cover 512*64 floats
    if (b < 128) gsum[b * 256 + tid] = 0.0f;
    __syncthreads();
    int base = boff[b];
    int end  = boff[b + 1];
    int node0 = b << BSHIFT;
    for (int i = base + tid; i < end; i += 256) {
        u64 e = ebuf[i];                               // coalesced 8B read
        int d = (int)(e >> 32);
        int pay = (int)(e & 0xffffffffu);
        int pos = atomicAdd(&cur[d - node0], 1);       // LDS atomic
        csr[(size_t)d * MAXDEG + pos] = pay;           // store within 49KB L2-local slab
    }
    __syncthreads();
    for (int r = tid; r < BUCKET_NODES; r += 256) {
        int d = node0 + r;
        if (d < N_NODES) cursor[d] = cur[r];
    }
}

// ---------------- K5: layer 1 agg + linear + relu, 8 lanes/node (bf16 out only) ----------------
__global__ __launch_bounds__(256) void agg1_lin1_kernel(
        const int* __restrict__ x_ids, const int* __restrict__ csr,
        const int* __restrict__ deg_arr, const us* __restrict__ e1b,
        const float* __restrict__ e1r, const float* __restrict__ b1,
        us* __restrict__ h1b) {
    int tid = blockIdx.x * blockDim.x + threadIdx.x;
    int lane = threadIdx.x & 63;
    int g = lane >> 3, c8 = lane & 7;
    int node = (tid >> 6) * 8 + g;
    bool valid = node < N_NODES;
    int nclamp = valid ? node : 0;
    int deg = valid ? deg_arr[nclamp] : 0;
    const int* crow = csr + (size_t)nclamp * MAXDEG;
    float a0=0.f,a1=0.f,a2=0.f,a3=0.f,a4=0.f,a5=0.f,a6=0.f,a7=0.f;
    for (int k = 0; k < deg; k += 4) {
        iv4 cv = *(const iv4*)(crow + k);      // 16B idx batch, broadcast within group
        #define GATH1(CVAL, T)                                                   \
        if (k + (T) < deg) {                                                     \
            int cls = (CVAL) >> 16;                                              \
            usv8 r = *(const usv8*)(e1b + cls * HID + c8 * 8);                   \
            a0 += bf2f(r[0]); a1 += bf2f(r[1]); a2 += bf2f(r[2]); a3 += bf2f(r[3]); \
            a4 += bf2f(r[4]); a5 += bf2f(r[5]); a6 += bf2f(r[6]); a7 += bf2f(r[7]); \
        }
        GATH1(cv.x, 0) GATH1(cv.y, 1) GATH1(cv.z, 2) GATH1(cv.w, 3)
        #undef GATH1
    }
    if (!valid) return;
    float inv = 1.0f / fmaxf((float)deg, 1.0f);
    int xid = x_ids[nclamp];
    const fv4* er = (const fv4*)(e1r + xid * HID + c8 * 8);
    fv4 e0 = er[0], e1v = er[1];
    const fv4* bb = (const fv4*)(b1 + c8 * 8);
    fv4 b0 = bb[0], b1v = bb[1];
    float h0 = fmaxf(a0 * inv + b0.x + e0.x, 0.0f);
    float h1 = fmaxf(a1 * inv + b0.y + e0.y, 0.0f);
    float h2 = fmaxf(a2 * inv + b0.z + e0.z, 0.0f);
    float h3 = fmaxf(a3 * inv + b0.w + e0.w, 0.0f);
    float h4 = fmaxf(a4 * inv + b1v.x + e1v.x, 0.0f);
    float h5 = fmaxf(a5 * inv + b1v.y + e1v.y, 0.0f);
    float h6 = fmaxf(a6 * inv + b1v.z + e1v.z, 0.0f);
    float h7 = fmaxf(a7 * inv + b1v.w + e1v.w, 0.0f);
    int o = node * HID + c8 * 8;
    usv8 hb;
    hb[0] = f2bf(h0); hb[1] = f2bf(h1); hb[2] = f2bf(h2); hb[3] = f2bf(h3);
    hb[4] = f2bf(h4); hb[5] = f2bf(h5); hb[6] = f2bf(h6); hb[7] = f2bf(h7);
    *(usv8*)(h1b + o) = hb;
}

// ---------------- K6: layer-2 aggregation, 8 lanes/node (bf16 mean out) ----------------
__global__ __launch_bounds__(256) void agg2_mean_kernel(
        const us* __restrict__ h1b, const int* __restrict__ csr,
        const int* __restrict__ deg_arr, us* __restrict__ mean2b) {
    int tid = blockIdx.x * blockDim.x + threadIdx.x;
    int lane = threadIdx.x & 63;
    int g = lane >> 3, c8 = lane & 7;
    int node = (tid >> 6) * 8 + g;
    bool valid = node < N_NODES;
    int nclamp = valid ? node : 0;
    int deg = valid ? deg_arr[nclamp] : 0;
    const int* crow = csr + (size_t)nclamp * MAXDEG;
    float a0=0.f,a1=0.f,a2=0.f,a3=0.f,a4=0.f,a5=0.f,a6=0.f,a7=0.f;
    for (int k = 0; k < deg; k += 4) {
        iv4 cv = *(const iv4*)(crow + k);
        #define GATH2(CVAL, T)                                                   \
        if (k + (T) < deg) {                                                     \
            int nb = (CVAL) & 0xFFFF;                                            \
            usv8 r = *(const usv8*)(h1b + nb * HID + c8 * 8);                    \
            a0 += bf2f(r[0]); a1 += bf2f(r[1]); a2 += bf2f(r[2]); a3 += bf2f(r[3]); \
            a4 += bf2f(r[4]); a5 += bf2f(r[5]); a6 += bf2f(r[6]); a7 += bf2f(r[7]); \
        }
        GATH2(cv.x, 0) GATH2(cv.y, 1) GATH2(cv.z, 2) GATH2(cv.w, 3)
        #undef GATH2
    }
    if (!valid) return;
    float inv = 1.0f / fmaxf((float)deg, 1.0f);
    int o = node * HID + c8 * 8;
    usv8 mb;
    mb[0] = f2bf(a0 * inv); mb[1] = f2bf(a1 * inv);
    mb[2] = f2bf(a2 * inv); mb[3] = f2bf(a3 * inv);
    mb[4] = f2bf(a4 * inv); mb[5] = f2bf(a5 * inv);
    mb[6] = f2bf(a6 * inv); mb[7] = f2bf(a7 * inv);
    *(usv8*)(mean2b + o) = mb;
}

// ---------------- K7: layer 2 linear + relu + pool (bf16 inputs, weights in VGPRs) ----------------
__global__ __launch_bounds__(256) void lin2_pool_kernel(
        const us* __restrict__ mean2b, const us* __restrict__ h1b,
        const float* __restrict__ w2l, const float* __restrict__ b2,
        const float* __restrict__ w2r, const int* __restrict__ batch,
        float* __restrict__ gsum) {
    int lane = threadIdx.x & 63;
    int wv = (blockIdx.x * blockDim.x + threadIdx.x) >> 6;   // global wave id
    int i0 = wv * L2P_CHUNK;
    int i1 = i0 + L2P_CHUNK; if (i1 > N_NODES) i1 = N_NODES;
    if (i0 >= N_NODES) return;
    float wl[HID], wr[HID];
    #pragma unroll
    for (int k = 0; k < HID; ++k) {
        wl[k] = w2l[k * HID + lane];
        wr[k] = w2r[k * HID + lane];
    }
    float bj = b2[lane];
    int curg = __builtin_amdgcn_readfirstlane(batch[i0]);
    float accp = 0.0f;
    float m = bf2f(mean2b[i0 * HID + lane]);
    float h = bf2f(h1b[i0 * HID + lane]);
    for (int i = i0; i < i1; ++i) {
        us mn_u = 0, hn_u = 0;
        if (i + 1 < i1) {                      // prefetch next rows
            mn_u = mean2b[(i + 1) * HID + lane];
            hn_u = h1b[(i + 1) * HID + lane];
        }
        int g = __builtin_amdgcn_readfirstlane(batch[i]);
        if (g != curg) {
            atomicAdd(&gsum[curg * HID + lane], accp);
            accp = 0.0f;
            curg = g;
        }
        float zm = 0.0f, zh = bj;              // split chains: 2x ILP on fma dep
        #pragma unroll
        for (int k = 0; k < HID; ++k) {
            zm = fmaf(rdlane(m, k), wl[k], zm);
            zh = fmaf(rdlane(h, k), wr[k], zh);
        }
        accp += fmaxf(zm + zh, 0.0f);
        m = bf2f(mn_u); h = bf2f(hn_u);
    }
    atomicAdd(&gsum[curg * HID + lane], accp);
}

// ---------------- K8: output: pool-normalize + final linear ----------------
__global__ void out_kernel(const float* __restrict__ gsum, const int* __restrict__ batch,
                           const float* __restrict__ w_out, const float* __restrict__ b_out,
                           float* __restrict__ out) {
    int id = blockIdx.x * blockDim.x + threadIdx.x;
    if (id >= N_GRAPHS * N_CLASS) return;
    int g = id >> 1, c = id & 1;
    int lo = 0, hi = N_NODES;
    while (lo < hi) { int mid = (lo + hi) >> 1; if (batch[mid] < g) lo = mid + 1; else hi = mid; }
    int first = lo;
    lo = 0; hi = N_NODES;
    while (lo < hi) { int mid = (lo + hi) >> 1; if (batch[mid] <= g) lo = mid + 1; else hi = mid; }
    float cnt = (float)(lo - first);
    float inv = 1.0f / fmaxf(cnt, 1.0f);
    float acc = b_out[c];
    #pragma unroll
    for (int j = 0; j < HID; ++j)
        acc = fmaf(gsum[g * HID + j] * inv, w_out[j * N_CLASS + c], acc);
    out[id] = acc;
}

// ---------------- launch: 8 dispatches ----------------

extern "C" void kernel_launch(void* const* d_in, const int* in_sizes, int n_in,
                              void* d_out, int out_size, void* d_ws, size_t ws_size,
                              hipStream_t stream) {
    const int*   x_ids = (const int*)d_in[0];
    const int*   edge  = (const int*)d_in[1];
    const int*   batch = (const int*)d_in[2];
    const float* embed = (const float*)d_in[3];
    const float* w1l   = (const float*)d_in[4];
    const float* b1    = (const float*)d_in[5];
    const float* w1r   = (const float*)d_in[6];
    const float* w2l   = (const float*)d_in[7];
    const float* b2    = (const float*)d_in[8];
    const float* w2r   = (const float*)d_in[9];
    const float* wout  = (const float*)d_in[10];
    const float* bout  = (const float*)d_in[11];
    const int* src = edge;
    const int* dst = edge + N_EDGES;
    float* out = (float*)d_out;

    char* ws = (char*)d_ws;
    size_t off = 0;
    auto alloc = [&](size_t bytes) -> void* {
        void* p = ws + off;
        off += (bytes + 255) & ~(size_t)255;
        return p;
    };
    us*     h1b    = (us*)alloc((size_t)N_NODES * HID * 2);             // 6.4 MB
    u64*    ebuf   = (u64*)alloc((size_t)N_EDGES * 8);                  // 12.8 MB
    int*    csr    = (int*)alloc((size_t)N_NODES * MAXDEG * 4);         // 19.2 MB
    int*    cursor = (int*)alloc((size_t)N_NODES * 4);                  // 200 KB
    int*    hist   = (int*)alloc((size_t)NBUCK * SORT_BLOCKS * 4);      // 611 KB
    int*    btot   = (int*)alloc((size_t)NBUCK * 4);
    int*    boff   = (int*)alloc((size_t)(NBUCK + 1) * 4);
    us*     e1b    = (us*)alloc((size_t)VOCAB * HID * 2);               // 128 KB
    float*  e1r    = (float*)alloc((size_t)VOCAB * HID * 4);            // 256 KB
    float*  gsum   = (float*)alloc((size_t)N_GRAPHS * HID * 4);         // 128 KB

    // mean2b aliases ebuf: ebuf is dead after csr_bucket; agg2_mean then
    // overwrites its first 6.4 MB (bf16 50000x64). Kernel-ordered, no overlap hazard.
    us* mean2b = (us*)ebuf;

    const int B = 256;
    pre_hist_kernel<<<SORT_BLOCKS + E1_BLOCKS, B, 0, stream>>>(dst, hist,
                                                               embed, w1l, w1r, e1b, e1r);
    scan_rows_kernel<<<NBUCK, B, 0, stream>>>(hist, btot);
    scatter_kernel<<<SORT_BLOCKS, B, 0, stream>>>(src, dst, x_ids, hist, btot, boff, ebuf);
    csr_bucket_kernel<<<NBUCK, B, 0, stream>>>(ebuf, boff, cursor, csr, gsum);
    agg1_lin1_kernel<<<AGG_BLOCKS, B, 0, stream>>>(x_ids, csr, cursor,
                                                   e1b, e1r, b1, h1b);
    agg2_mean_kernel<<<AGG_BLOCKS, B, 0, stream>>>(h1b, csr, cursor, mean2b);
    lin2_pool_kernel<<<L2P_BLOCKS, B, 0, stream>>>(mean2b, h1b, w2l, b2, w2r, batch, gsum);
    out_kernel<<<(N_GRAPHS * N_CLASS + B - 1) / B, B, 0, stream>>>(gsum, batch, wout, bout, out);
}

// Round 12
// 200.949 us; speedup vs baseline: 1.2724x; 1.0894x over previous
//
#include <hip/hip_runtime.h>
#include <hip/hip_bf16.h>

#define N_NODES 50000
#define N_EDGES 1600000
#define N_GRAPHS 512
#define VOCAB 1000
#define EMB 32
#define HID 64
#define N_CLASS 2

#define MAXDEG 96                      // Poisson(32) tail @96 ~ 4e-20/node

// ---- atomic-free CSR build (counting bucket-sort) ----
#define NVEC (N_EDGES / 4)             // 400000 int4 vectors
#define SORT_VPB 1024                  // vectors per block (256 thr x 4)
#define SORT_EPB (SORT_VPB * 4)        // 4096 edges per block
#define SORT_BLOCKS ((NVEC + SORT_VPB - 1) / SORT_VPB)   // 391
#define BSHIFT 7
#define BUCKET_NODES 128
#define NBUCK ((N_NODES + BUCKET_NODES - 1) / BUCKET_NODES)  // 391

#define E1_BLOCKS ((VOCAB * HID + 255) / 256)            // 250

// ---- agg kernels: 8 lanes per node, 8 nodes per wave ----
#define AGG_THREADS (N_NODES * 8)
#define AGG_BLOCKS ((AGG_THREADS + 255) / 256)           // 1563

// ---- lin2_pool: weights in VGPRs, 17 nodes per wave ----
#define L2P_BLOCKS 768                 // 3 blocks/CU co-resident
#define L2P_WAVES (L2P_BLOCKS * 4)     // 3072
#define L2P_CHUNK ((N_NODES + L2P_WAVES - 1) / L2P_WAVES)  // 17

typedef int iv4 __attribute__((ext_vector_type(4)));
typedef unsigned short us;
typedef us usv8 __attribute__((ext_vector_type(8)));
typedef float fv4 __attribute__((ext_vector_type(4)));
typedef unsigned long long u64;

__device__ __forceinline__ float bf2f(us u) {
    union { unsigned int i; float f; } c;
    c.i = ((unsigned int)u) << 16;
    return c.f;
}
__device__ __forceinline__ us f2bf(float f) {
    union { __hip_bfloat16 b; us u; } c;
    c.b = __float2bfloat16(f);
    return c.u;
}
__device__ __forceinline__ float rdlane(float v, int k) {
    return __int_as_float(__builtin_amdgcn_readlane(__float_as_int(v), k));
}

// ---------------- K1: fused precompute_e1 + per-block bucket histogram ----------------
__global__ __launch_bounds__(256) void pre_hist_kernel(
        const int* __restrict__ dst, int* __restrict__ hist,
        const float* __restrict__ embed, const float* __restrict__ w1l,
        const float* __restrict__ w1r, us* __restrict__ e1b,
        float* __restrict__ e1r) {
    __shared__ int lh[NBUCK];
    if (blockIdx.x < SORT_BLOCKS) {
        for (int b = threadIdx.x; b < NBUCK; b += 256) lh[b] = 0;
        __syncthreads();
        const iv4* dst4 = (const iv4*)dst;
        int vbase = blockIdx.x * SORT_VPB;
        #pragma unroll
        for (int t = 0; t < 4; ++t) {
            int v = vbase + t * 256 + threadIdx.x;
            if (v < NVEC) {
                iv4 d4 = __builtin_nontemporal_load(&dst4[v]);
                atomicAdd(&lh[d4.x >> BSHIFT], 1);
                atomicAdd(&lh[d4.y >> BSHIFT], 1);
                atomicAdd(&lh[d4.z >> BSHIFT], 1);
                atomicAdd(&lh[d4.w >> BSHIFT], 1);
            }
        }
        __syncthreads();
        for (int b = threadIdx.x; b < NBUCK; b += 256)
            hist[b * SORT_BLOCKS + blockIdx.x] = lh[b];
    } else {
        int id = (blockIdx.x - SORT_BLOCKS) * 256 + threadIdx.x;
        if (id >= VOCAB * HID) return;
        int v = id >> 6, j = id & 63;
        float a = 0.0f, b = 0.0f;
        #pragma unroll
        for (int k = 0; k < EMB; ++k) {
            float ev = embed[v * EMB + k];
            a = fmaf(ev, w1l[k * HID + j], a);
            b = fmaf(ev, w1r[k * HID + j], b);
        }
        e1b[id] = f2bf(a);
        e1r[id] = b;
    }
}

// ---------------- K2: per-bucket exclusive scan over its SORT_BLOCKS counters ----------------
__global__ __launch_bounds__(256) void scan_rows_kernel(int* __restrict__ hist,
                                                        int* __restrict__ btot) {
    int* row = hist + (size_t)blockIdx.x * SORT_BLOCKS;
    __shared__ int wsum[4];
    int tid = threadIdx.x, lane = tid & 63, w = tid >> 6;
    int carry = 0;
    for (int base = 0; base < SORT_BLOCKS; base += 256) {
        int idx = base + tid;
        int v = (idx < SORT_BLOCKS) ? row[idx] : 0;
        int inc = v;
        #pragma unroll
        for (int off = 1; off < 64; off <<= 1) {
            int n = __shfl_up(inc, off, 64);
            if (lane >= off) inc += n;
        }
        if (lane == 63) wsum[w] = inc;
        __syncthreads();
        int woff = 0;
        #pragma unroll
        for (int k = 0; k < 4; ++k) if (k < w) woff += wsum[k];
        if (idx < SORT_BLOCKS) row[idx] = carry + woff + inc - v;
        carry += wsum[0] + wsum[1] + wsum[2] + wsum[3];
        __syncthreads();
    }
    if (tid == 0) btot[blockIdx.x] = carry;
}

// ---------------- K3: scatter with block-local LDS counting sort ----------------
// Edges are bucket-sorted in LDS first, so the global ebuf stores are emitted as
// contiguous runs (consecutive lanes -> consecutive addresses) instead of 64
// isolated 8B stores per wave (~8x write amplification observed for that pattern).
__global__ __launch_bounds__(256) void scatter_kernel(const int* __restrict__ src,
        const int* __restrict__ dst, const int* __restrict__ x_ids,
        const int* __restrict__ hist, const int* __restrict__ btot,
        int* __restrict__ boff, u64* __restrict__ ebuf) {
    __shared__ u64 ebuf_l[SORT_EPB];   // 32 KB, bucket-ordered entries
    __shared__ int lh[NBUCK];          // counts -> later write-out base (gbase - lstart)
    __shared__ int lstart[NBUCK];      // block-local exclusive starts
    __shared__ int lcur[NBUCK];        // allocation cursors
    __shared__ int wsum[4];
    int tid = threadIdx.x, lane = tid & 63, w = tid >> 6;
    int blk = blockIdx.x;

    // ---- load this block's edge chunk into registers ----
    const iv4* dst4 = (const iv4*)dst;
    const iv4* src4 = (const iv4*)src;
    int vbase = blk * SORT_VPB;
    iv4 d4s[4], s4s[4];
    bool vok[4];
    #pragma unroll
    for (int t = 0; t < 4; ++t) {
        int v = vbase + t * 256 + tid;
        vok[t] = (v < NVEC);
        if (vok[t]) {
            d4s[t] = __builtin_nontemporal_load(&dst4[v]);
            s4s[t] = __builtin_nontemporal_load(&src4[v]);
        }
    }

    // ---- phase 1: block-local histogram ----
    for (int b = tid; b < NBUCK; b += 256) lh[b] = 0;
    __syncthreads();
    #pragma unroll
    for (int t = 0; t < 4; ++t) {
        if (vok[t]) {
            atomicAdd(&lh[d4s[t].x >> BSHIFT], 1);
            atomicAdd(&lh[d4s[t].y >> BSHIFT], 1);
            atomicAdd(&lh[d4s[t].z >> BSHIFT], 1);
            atomicAdd(&lh[d4s[t].w >> BSHIFT], 1);
        }
    }
    __syncthreads();

    // ---- phase 2: exclusive scan of lh -> lstart (copy to lcur); total in carry ----
    int carry = 0;
    for (int base = 0; base < NBUCK; base += 256) {
        int idx = base + tid;
        int v = (idx < NBUCK) ? lh[idx] : 0;
        int inc = v;
        #pragma unroll
        for (int off = 1; off < 64; off <<= 1) {
            int n = __shfl_up(inc, off, 64);
            if (lane >= off) inc += n;
        }
        if (lane == 63) wsum[w] = inc;
        __syncthreads();
        int woff = 0;
        #pragma unroll
        for (int k = 0; k < 4; ++k) if (k < w) woff += wsum[k];
        if (idx < NBUCK) {
            int ex = carry + woff + inc - v;
            lstart[idx] = ex;
            lcur[idx] = ex;
        }
        carry += wsum[0] + wsum[1] + wsum[2] + wsum[3];
        __syncthreads();
    }
    int total = carry;                 // edges in this block

    // ---- phase 3: place entries bucket-ordered in LDS ----
    #pragma unroll
    for (int t = 0; t < 4; ++t) {
        if (vok[t]) {
            iv4 d4 = d4s[t], s4 = s4s[t];
            int pay0 = (x_ids[s4.x] << 16) | s4.x;
            int pay1 = (x_ids[s4.y] << 16) | s4.y;
            int pay2 = (x_ids[s4.z] << 16) | s4.z;
            int pay3 = (x_ids[s4.w] << 16) | s4.w;
            int p0 = atomicAdd(&lcur[d4.x >> BSHIFT], 1);
            int p1 = atomicAdd(&lcur[d4.y >> BSHIFT], 1);
            int p2 = atomicAdd(&lcur[d4.z >> BSHIFT], 1);
            int p3 = atomicAdd(&lcur[d4.w >> BSHIFT], 1);
            ebuf_l[p0] = ((u64)(unsigned)d4.x << 32) | (unsigned)pay0;
            ebuf_l[p1] = ((u64)(unsigned)d4.y << 32) | (unsigned)pay1;
            ebuf_l[p2] = ((u64)(unsigned)d4.z << 32) | (unsigned)pay2;
            ebuf_l[p3] = ((u64)(unsigned)d4.w << 32) | (unsigned)pay3;
        }
    }
    __syncthreads();

    // ---- phase 4: scan btot -> global bucket bases; lh[b] = boff[b]+hist[b][blk]-lstart[b] ----
    carry = 0;
    for (int base = 0; base < NBUCK; base += 256) {
        int idx = base + tid;
        int v = (idx < NBUCK) ? btot[idx] : 0;
        int inc = v;
        #pragma unroll
        for (int off = 1; off < 64; off <<= 1) {
            int n = __shfl_up(inc, off, 64);
            if (lane >= off) inc += n;
        }
        if (lane == 63) wsum[w] = inc;
        __syncthreads();
        int woff = 0;
        #pragma unroll
        for (int k = 0; k < 4; ++k) if (k < w) woff += wsum[k];
        if (idx < NBUCK) {
            int gb = carry + woff + inc - v;           // boff[idx]
            if (blk == 0) boff[idx] = gb;
            lh[idx] = gb + hist[idx * SORT_BLOCKS + blk] - lstart[idx];
        }
        carry += wsum[0] + wsum[1] + wsum[2] + wsum[3];
        __syncthreads();
    }
    if (blk == 0 && tid == 0) boff[NBUCK] = carry;
    __syncthreads();

    // ---- phase 5: coalesced write-out (consecutive slots -> consecutive addrs per run) ----
    for (int i = tid; i < total; i += 256) {
        u64 e = ebuf_l[i];
        int b = (int)(e >> (32 + BSHIFT));             // bucket from dst field
        ebuf[lh[b] + i] = e;
    }
}

// ---------------- K4: per-bucket CSR build (LDS cursors only, 512B LDS) ----------------
__global__ __launch_bounds__(256) void csr_bucket_kernel(const u64* __restrict__ ebuf,
        const int* __restrict__ boff, int* __restrict__ cursor, int* __restrict__ csr,
        float* __restrict__ gsum) {
    int b = blockIdx.x;
    int tid = threadIdx.x;
    __shared__ int cur[BUCKET_NODES];
    for (int r = tid; r < BUCKET_NODES; r += 256) cur[r] = 0;
    // zero gsum (replaces a memset dispatch): blocks 0..127 cover 512*64 floats
    if (b < 128) gsum[b * 256 + tid] = 0.0f;
    __syncthreads();
    int base = boff[b];
    int end  = boff[b + 1];
    int node0 = b << BSHIFT;
    for (int i = base + tid; i < end; i += 256) {
        u64 e = ebuf[i];                               // coalesced 8B read
        int d = (int)(e >> 32);
        int pay = (int)(e & 0xffffffffu);
        int pos = atomicAdd(&cur[d - node0], 1);       // LDS atomic
        csr[(size_t)d * MAXDEG + pos] = pay;           // store within 49KB L2-local slab
    }
    __syncthreads();
    for (int r = tid; r < BUCKET_NODES; r += 256) {
        int d = node0 + r;
        if (d < N_NODES) cursor[d] = cur[r];
    }
}

// ---------------- K5: layer 1 agg + linear + relu, 8 lanes/node (bf16 out only) ----------------
__global__ __launch_bounds__(256) void agg1_lin1_kernel(
        const int* __restrict__ x_ids, const int* __restrict__ csr,
        const int* __restrict__ deg_arr, const us* __restrict__ e1b,
        const float* __restrict__ e1r, const float* __restrict__ b1,
        us* __restrict__ h1b) {
    int tid = blockIdx.x * blockDim.x + threadIdx.x;
    int lane = threadIdx.x & 63;
    int g = lane >> 3, c8 = lane & 7;
    int node = (tid >> 6) * 8 + g;
    bool valid = node < N_NODES;
    int nclamp = valid ? node : 0;
    int deg = valid ? deg_arr[nclamp] : 0;
    const int* crow = csr + (size_t)nclamp * MAXDEG;
    float a0=0.f,a1=0.f,a2=0.f,a3=0.f,a4=0.f,a5=0.f,a6=0.f,a7=0.f;
    for (int k = 0; k < deg; k += 4) {
        iv4 cv = *(const iv4*)(crow + k);      // 16B idx batch, broadcast within group
        #define GATH1(CVAL, T)                                                   \
        if (k + (T) < deg) {                                                     \
            int cls = (CVAL) >> 16;                                              \
            usv8 r = *(const usv8*)(e1b + cls * HID + c8 * 8);                   \
            a0 += bf2f(r[0]); a1 += bf2f(r[1]); a2 += bf2f(r[2]); a3 += bf2f(r[3]); \
            a4 += bf2f(r[4]); a5 += bf2f(r[5]); a6 += bf2f(r[6]); a7 += bf2f(r[7]); \
        }
        GATH1(cv.x, 0) GATH1(cv.y, 1) GATH1(cv.z, 2) GATH1(cv.w, 3)
        #undef GATH1
    }
    if (!valid) return;
    float inv = 1.0f / fmaxf((float)deg, 1.0f);
    int xid = x_ids[nclamp];
    const fv4* er = (const fv4*)(e1r + xid * HID + c8 * 8);
    fv4 e0 = er[0], e1v = er[1];
    const fv4* bb = (const fv4*)(b1 + c8 * 8);
    fv4 b0 = bb[0], b1v = bb[1];
    float h0 = fmaxf(a0 * inv + b0.x + e0.x, 0.0f);
    float h1 = fmaxf(a1 * inv + b0.y + e0.y, 0.0f);
    float h2 = fmaxf(a2 * inv + b0.z + e0.z, 0.0f);
    float h3 = fmaxf(a3 * inv + b0.w + e0.w, 0.0f);
    float h4 = fmaxf(a4 * inv + b1v.x + e1v.x, 0.0f);
    float h5 = fmaxf(a5 * inv + b1v.y + e1v.y, 0.0f);
    float h6 = fmaxf(a6 * inv + b1v.z + e1v.z, 0.0f);
    float h7 = fmaxf(a7 * inv + b1v.w + e1v.w, 0.0f);
    int o = node * HID + c8 * 8;
    usv8 hb;
    hb[0] = f2bf(h0); hb[1] = f2bf(h1); hb[2] = f2bf(h2); hb[3] = f2bf(h3);
    hb[4] = f2bf(h4); hb[5] = f2bf(h5); hb[6] = f2bf(h6); hb[7] = f2bf(h7);
    *(usv8*)(h1b + o) = hb;
}

// ---------------- K6: layer-2 aggregation, 8 lanes/node (bf16 mean out) ----------------
__global__ __launch_bounds__(256) void agg2_mean_kernel(
        const us* __restrict__ h1b, const int* __restrict__ csr,
        const int* __restrict__ deg_arr, us* __restrict__ mean2b) {
    int tid = blockIdx.x * blockDim.x + threadIdx.x;
    int lane = threadIdx.x & 63;
    int g = lane >> 3, c8 = lane & 7;
    int node = (tid >> 6) * 8 + g;
    bool valid = node < N_NODES;
    int nclamp = valid ? node : 0;
    int deg = valid ? deg_arr[nclamp] : 0;
    const int* crow = csr + (size_t)nclamp * MAXDEG;
    float a0=0.f,a1=0.f,a2=0.f,a3=0.f,a4=0.f,a5=0.f,a6=0.f,a7=0.f;
    for (int k = 0; k < deg; k += 4) {
        iv4 cv = *(const iv4*)(crow + k);
        #define GATH2(CVAL, T)                                                   \
        if (k + (T) < deg) {                                                     \
            int nb = (CVAL) & 0xFFFF;                                            \
            usv8 r = *(const usv8*)(h1b + nb * HID + c8 * 8);                    \
            a0 += bf2f(r[0]); a1 += bf2f(r[1]); a2 += bf2f(r[2]); a3 += bf2f(r[3]); \
            a4 += bf2f(r[4]); a5 += bf2f(r[5]); a6 += bf2f(r[6]); a7 += bf2f(r[7]); \
        }
        GATH2(cv.x, 0) GATH2(cv.y, 1) GATH2(cv.z, 2) GATH2(cv.w, 3)
        #undef GATH2
    }
    if (!valid) return;
    float inv = 1.0f / fmaxf((float)deg, 1.0f);
    int o = node * HID + c8 * 8;
    usv8 mb;
    mb[0] = f2bf(a0 * inv); mb[1] = f2bf(a1 * inv);
    mb[2] = f2bf(a2 * inv); mb[3] = f2bf(a3 * inv);
    mb[4] = f2bf(a4 * inv); mb[5] = f2bf(a5 * inv);
    mb[6] = f2bf(a6 * inv); mb[7] = f2bf(a7 * inv);
    *(usv8*)(mean2b + o) = mb;
}

// ---------------- K7: layer 2 linear + relu + pool (bf16 inputs, weights in VGPRs) ----------------
__global__ __launch_bounds__(256) void lin2_pool_kernel(
        const us* __restrict__ mean2b, const us* __restrict__ h1b,
        const float* __restrict__ w2l, const float* __restrict__ b2,
        const float* __restrict__ w2r, const int* __restrict__ batch,
        float* __restrict__ gsum) {
    int lane = threadIdx.x & 63;
    int wv = (blockIdx.x * blockDim.x + threadIdx.x) >> 6;   // global wave id
    int i0 = wv * L2P_CHUNK;
    int i1 = i0 + L2P_CHUNK; if (i1 > N_NODES) i1 = N_NODES;
    if (i0 >= N_NODES) return;
    float wl[HID], wr[HID];
    #pragma unroll
    for (int k = 0; k < HID; ++k) {
        wl[k] = w2l[k * HID + lane];
        wr[k] = w2r[k * HID + lane];
    }
    float bj = b2[lane];
    int curg = __builtin_amdgcn_readfirstlane(batch[i0]);
    float accp = 0.0f;
    float m = bf2f(mean2b[i0 * HID + lane]);
    float h = bf2f(h1b[i0 * HID + lane]);
    for (int i = i0; i < i1; ++i) {
        us mn_u = 0, hn_u = 0;
        if (i + 1 < i1) {                      // prefetch next rows
            mn_u = mean2b[(i + 1) * HID + lane];
            hn_u = h1b[(i + 1) * HID + lane];
        }
        int g = __builtin_amdgcn_readfirstlane(batch[i]);
        if (g != curg) {
            atomicAdd(&gsum[curg * HID + lane], accp);
            accp = 0.0f;
            curg = g;
        }
        float zm = 0.0f, zh = bj;              // split chains: 2x ILP on fma dep
        #pragma unroll
        for (int k = 0; k < HID; ++k) {
            zm = fmaf(rdlane(m, k), wl[k], zm);
            zh = fmaf(rdlane(h, k), wr[k], zh);
        }
        accp += fmaxf(zm + zh, 0.0f);
        m = bf2f(mn_u); h = bf2f(hn_u);
    }
    atomicAdd(&gsum[curg * HID + lane], accp);
}

// ---------------- K8: output: pool-normalize + final linear ----------------
__global__ void out_kernel(const float* __restrict__ gsum, const int* __restrict__ batch,
                           const float* __restrict__ w_out, const float* __restrict__ b_out,
                           float* __restrict__ out) {
    int id = blockIdx.x * blockDim.x + threadIdx.x;
    if (id >= N_GRAPHS * N_CLASS) return;
    int g = id >> 1, c = id & 1;
    int lo = 0, hi = N_NODES;
    while (lo < hi) { int mid = (lo + hi) >> 1; if (batch[mid] < g) lo = mid + 1; else hi = mid; }
    int first = lo;
    lo = 0; hi = N_NODES;
    while (lo < hi) { int mid = (lo + hi) >> 1; if (batch[mid] <= g) lo = mid + 1; else hi = mid; }
    float cnt = (float)(lo - first);
    float inv = 1.0f / fmaxf(cnt, 1.0f);
    float acc = b_out[c];
    #pragma unroll
    for (int j = 0; j < HID; ++j)
        acc = fmaf(gsum[g * HID + j] * inv, w_out[j * N_CLASS + c], acc);
    out[id] = acc;
}

// ---------------- launch: 8 dispatches ----------------

extern "C" void kernel_launch(void* const* d_in, const int* in_sizes, int n_in,
                              void* d_out, int out_size, void* d_ws, size_t ws_size,
                              hipStream_t stream) {
    const int*   x_ids = (const int*)d_in[0];
    const int*   edge  = (const int*)d_in[1];
    const int*   batch = (const int*)d_in[2];
    const float* embed = (const float*)d_in[3];
    const float* w1l   = (const float*)d_in[4];
    const float* b1    = (const float*)d_in[5];
    const float* w1r   = (const float*)d_in[6];
    const float* w2l   = (const float*)d_in[7];
    const float* b2    = (const float*)d_in[8];
    const float* w2r   = (const float*)d_in[9];
    const float* wout  = (const float*)d_in[10];
    const float* bout  = (const float*)d_in[11];
    const int* src = edge;
    const int* dst = edge + N_EDGES;
    float* out = (float*)d_out;

    char* ws = (char*)d_ws;
    size_t off = 0;
    auto alloc = [&](size_t bytes) -> void* {
        void* p = ws + off;
        off += (bytes + 255) & ~(size_t)255;
        return p;
    };
    us*     h1b    = (us*)alloc((size_t)N_NODES * HID * 2);             // 6.4 MB
    u64*    ebuf   = (u64*)alloc((size_t)N_EDGES * 8);                  // 12.8 MB
    int*    csr    = (int*)alloc((size_t)N_NODES * MAXDEG * 4);         // 19.2 MB
    int*    cursor = (int*)alloc((size_t)N_NODES * 4);                  // 200 KB
    int*    hist   = (int*)alloc((size_t)NBUCK * SORT_BLOCKS * 4);      // 611 KB
    int*    btot   = (int*)alloc((size_t)NBUCK * 4);
    int*    boff   = (int*)alloc((size_t)(NBUCK + 1) * 4);
    us*     e1b    = (us*)alloc((size_t)VOCAB * HID * 2);               // 128 KB
    float*  e1r    = (float*)alloc((size_t)VOCAB * HID * 4);            // 256 KB
    float*  gsum   = (float*)alloc((size_t)N_GRAPHS * HID * 4);         // 128 KB

    // mean2b aliases ebuf: ebuf is dead after csr_bucket; agg2_mean then
    // overwrites its first 6.4 MB (bf16 50000x64). Kernel-ordered, no overlap hazard.
    us* mean2b = (us*)ebuf;

    const int B = 256;
    pre_hist_kernel<<<SORT_BLOCKS + E1_BLOCKS, B, 0, stream>>>(dst, hist,
                                                               embed, w1l, w1r, e1b, e1r);
    scan_rows_kernel<<<NBUCK, B, 0, stream>>>(hist, btot);
    scatter_kernel<<<SORT_BLOCKS, B, 0, stream>>>(src, dst, x_ids, hist, btot, boff, ebuf);
    csr_bucket_kernel<<<NBUCK, B, 0, stream>>>(ebuf, boff, cursor, csr, gsum);
    agg1_lin1_kernel<<<AGG_BLOCKS, B, 0, stream>>>(x_ids, csr, cursor,
                                                   e1b, e1r, b1, h1b);
    agg2_mean_kernel<<<AGG_BLOCKS, B, 0, stream>>>(h1b, csr, cursor, mean2b);
    lin2_pool_kernel<<<L2P_BLOCKS, B, 0, stream>>>(mean2b, h1b, w2l, b2, w2r, batch, gsum);
    out_kernel<<<(N_GRAPHS * N_CLASS + B - 1) / B, B, 0, stream>>>(gsum, batch, wout, bout, out);
}